// Round 1
// baseline (856.605 us; speedup 1.0000x reference)
//
#include <hip/hip_runtime.h>
#include <hip/hip_bf16.h>

#define DM 1024
#define DI 2048
#define LSEQ 1024
#define BSZ 2
#define NROWS (BSZ*LSEQ)   // 2048

typedef __attribute__((ext_vector_type(4))) float f32x4;
typedef __attribute__((ext_vector_type(8))) short bf16x8;
typedef __hip_bfloat16 bf16;

__device__ __forceinline__ float sigmoidf_(float x){ return 1.f/(1.f+__expf(-x)); }

// ---------------- f32 -> bf16 convert (optional row-pad / row-stride) ----------------
__global__ void cvt_kernel(const float* __restrict__ src, bf16* __restrict__ dst,
                           long n, int cols, int src_stride, int src_rows)
{
  long i = (long)blockIdx.x*blockDim.x + threadIdx.x;
  if (i >= n) return;
  int r = (int)(i / cols);
  int c = (int)(i - (long)r*cols);
  float v = (r < src_rows) ? src[(long)r*src_stride + c] : 0.f;
  dst[i] = __float2bfloat16(v);
}

// ---------------- LayerNorm (row=1024) f32 -> bf16 ----------------
__global__ __launch_bounds__(256) void ln_kernel(const float* __restrict__ x,
    const float* __restrict__ g, const float* __restrict__ b, bf16* __restrict__ out)
{
  int row = blockIdx.x;
  float4 v = ((const float4*)(x + (long)row*DM))[threadIdx.x];
  float s  = v.x+v.y+v.z+v.w;
  float s2 = v.x*v.x+v.y*v.y+v.z*v.z+v.w*v.w;
  #pragma unroll
  for (int m=32;m;m>>=1){ s += __shfl_xor(s,m); s2 += __shfl_xor(s2,m); }
  __shared__ float ws0[4], ws1[4];
  int wv = threadIdx.x>>6;
  if ((threadIdx.x&63)==0){ ws0[wv]=s; ws1[wv]=s2; }
  __syncthreads();
  s  = ws0[0]+ws0[1]+ws0[2]+ws0[3];
  s2 = ws1[0]+ws1[1]+ws1[2]+ws1[3];
  float mu  = s*(1.f/DM);
  float var = s2*(1.f/DM) - mu*mu;
  float rs  = rsqrtf(var + 1e-5f);
  int c = threadIdx.x*4;
  float4 gg = ((const float4*)g)[threadIdx.x];
  float4 bb = ((const float4*)b)[threadIdx.x];
  bf16* o = out + (long)row*DM + c;
  o[0] = __float2bfloat16((v.x-mu)*rs*gg.x + bb.x);
  o[1] = __float2bfloat16((v.y-mu)*rs*gg.y + bb.y);
  o[2] = __float2bfloat16((v.z-mu)*rs*gg.z + bb.z);
  o[3] = __float2bfloat16((v.w-mu)*rs*gg.w + bb.w);
}

// ---------------- bf16 MFMA GEMM: C[M,N] = A[M,K] @ B[N,K]^T (+bias)(+act)(+res) ----
// 128x128 tile, 256 threads (4 waves), each wave 64x64 via 4x4 frags of 16x16x32.
// ACT: 0=none, 1=softplus
template<int ACT>
__global__ __launch_bounds__(256)
void gemm_k(const short* __restrict__ A, const short* __restrict__ B,
            int K, int Nreal,
            const float* __restrict__ bias, const float* __restrict__ res,
            float* __restrict__ outf, bf16* __restrict__ outb)
{
  __shared__ short As[128*32];
  __shared__ short Bs[128*32];
  const int tid  = threadIdx.x;
  const int wave = tid>>6, lane = tid&63;
  const int m0 = blockIdx.x*128, n0 = blockIdx.y*128;
  const int wm = (wave>>1)*64, wn = (wave&1)*64;
  const int lr = lane&15, lk = lane>>4;

  f32x4 acc[4][4];
  #pragma unroll
  for (int i=0;i<4;i++)
    #pragma unroll
    for (int j=0;j<4;j++) acc[i][j] = f32x4{0.f,0.f,0.f,0.f};

  const int r0 = tid>>2;        // 0..63
  const int kb = (tid&3)*8;     // 0,8,16,24 (bf16 elems)

  for (int kt=0; kt<K; kt+=32) {
    #pragma unroll
    for (int i=0;i<2;i++){
      int row = r0 + i*64;
      __builtin_amdgcn_global_load_lds(
        (const __attribute__((address_space(1))) void*)(A + (size_t)(m0+row)*K + kt + kb),
        (__attribute__((address_space(3))) void*)(As + row*32 + kb), 16, 0, 0);
    }
    #pragma unroll
    for (int i=0;i<2;i++){
      int row = r0 + i*64;
      __builtin_amdgcn_global_load_lds(
        (const __attribute__((address_space(1))) void*)(B + (size_t)(n0+row)*K + kt + kb),
        (__attribute__((address_space(3))) void*)(Bs + row*32 + kb), 16, 0, 0);
    }
    asm volatile("s_waitcnt vmcnt(0)");
    __syncthreads();
    bf16x8 af[4], bfr[4];
    #pragma unroll
    for (int i=0;i<4;i++) af[i]  = *(const bf16x8*)(As + (wm+i*16+lr)*32 + lk*8);
    #pragma unroll
    for (int j=0;j<4;j++) bfr[j] = *(const bf16x8*)(Bs + (wn+j*16+lr)*32 + lk*8);
    #pragma unroll
    for (int i=0;i<4;i++)
      #pragma unroll
      for (int j=0;j<4;j++)
        acc[i][j] = __builtin_amdgcn_mfma_f32_16x16x32_bf16(af[i], bfr[j], acc[i][j], 0,0,0);
    __syncthreads();
  }

  // epilogue: C/D map col=lane&15, row=(lane>>4)*4+reg   [m89-verified]
  #pragma unroll
  for (int i=0;i<4;i++){
    #pragma unroll
    for (int j=0;j<4;j++){
      int col = n0 + wn + j*16 + lr;
      if (col >= Nreal) continue;
      #pragma unroll
      for (int r=0;r<4;r++){
        int row = m0 + wm + i*16 + lk*4 + r;
        float v = acc[i][j][r];
        if (bias) v += bias[col];
        if (ACT==1) v = (v > 20.f) ? v : log1pf(__expf(v));
        if (res)  v += res[(size_t)row*Nreal + col];
        if (outf) outf[(size_t)row*Nreal + col] = v;
        if (outb) outb[(size_t)row*Nreal + col] = __float2bfloat16(v);
      }
    }
  }
}

// ---------------- depthwise causal conv(4) + silu; writes f32 + bf16 ----------------
__global__ __launch_bounds__(256) void conv_kernel(const bf16* __restrict__ xz,
    const float* __restrict__ w, const float* __restrict__ cb,
    float* __restrict__ xcf, bf16* __restrict__ xcb)
{
  long i = (long)blockIdx.x*blockDim.x + threadIdx.x;  // NROWS*DI
  int d  = (int)(i & (DI-1));
  int bl = (int)(i >> 11);
  int l  = bl & (LSEQ-1);
  int b  = bl >> 10;
  float acc = cb[d];
  #pragma unroll
  for (int k=0;k<4;k++){
    int ls = l-3+k;
    if (ls >= 0)
      acc += __bfloat162float(xz[(long)(b*LSEQ+ls)*(2*DI) + d]) * w[d*4+k];
  }
  float s = acc * sigmoidf_(acc);
  xcf[i] = s;
  xcb[i] = __float2bfloat16(s);
}

// ---------------- SSM scan: block = 16 channels x 16 states, chunked over L --------
__global__ __launch_bounds__(256) void scan_kernel(
    const float* __restrict__ delta, const float* __restrict__ xc,
    const float* __restrict__ xdbl, const bf16* __restrict__ xz,
    const float* __restrict__ A_log, const float* __restrict__ Dp,
    bf16* __restrict__ y)
{
  int blk = blockIdx.x;              // 256 blocks: b (2) x d-group (128)
  int b = blk>>7, d0 = (blk&127)*16;
  int t = threadIdx.x;
  int dl = t>>4, n = t&15;
  int d = d0 + dl;
  float Aneg = -__expf(A_log[d*16 + n]);
  float Dd = Dp[d];
  __shared__ float sD[64][16], sX[64][16], sB[64][16], sC[64][16], sZ[64][16];
  float h = 0.f;
  const long base = (long)b*LSEQ;
  for (int l0=0; l0<LSEQ; l0+=64) {
    __syncthreads();
    #pragma unroll
    for (int i=0;i<4;i++){
      int ll = (t>>4) + i*16;
      int dd = t&15;
      long row = base + l0 + ll;
      sD[ll][dd] = delta[row*DI + d0+dd];
      sX[ll][dd] = xc[row*DI + d0+dd];
      sB[ll][dd] = xdbl[row*96 + 64 + dd];
      sC[ll][dd] = xdbl[row*96 + 80 + dd];
      sZ[ll][dd] = __bfloat162float(xz[row*(2*DI) + DI + d0+dd]);
    }
    __syncthreads();
    #pragma unroll 4
    for (int ll=0; ll<64; ll++){
      float du = sD[ll][dl], xv = sX[ll][dl];
      float a = __expf(du*Aneg);
      h = a*h + du*xv*sB[ll][n];
      float r = h*sC[ll][n];
      r += __shfl_xor(r,8); r += __shfl_xor(r,4);
      r += __shfl_xor(r,2); r += __shfl_xor(r,1);
      if (n==0) {
        float z = sZ[ll][dl];
        float yo = (r + xv*Dd) * (z * sigmoidf_(z));
        y[(base+l0+ll)*DI + d] = __float2bfloat16(yo);
      }
    }
  }
}

// ---------------- gated: g = silu(gv[:, :1024]) * gv[:, 1024:] -> bf16 -------------
__global__ __launch_bounds__(256) void gated_kernel(const float* __restrict__ gv,
                                                    bf16* __restrict__ g)
{
  long i = (long)blockIdx.x*blockDim.x + threadIdx.x;  // NROWS*DM
  int r = (int)(i >> 10);
  int c = (int)(i & (DM-1));
  float gt = gv[(long)r*(2*DM) + c];
  float vl = gv[(long)r*(2*DM) + DM + c];
  g[i] = __float2bfloat16(gt * sigmoidf_(gt) * vl);
}

// ------------------------------- launcher ------------------------------------------
extern "C" void kernel_launch(void* const* d_in, const int* in_sizes, int n_in,
                              void* d_out, int out_size, void* d_ws, size_t ws_size,
                              hipStream_t stream)
{
  const float* x        = (const float*)d_in[0];
  const float* n1_g     = (const float*)d_in[1];
  const float* n1_b     = (const float*)d_in[2];
  const float* n2_g     = (const float*)d_in[3];
  const float* n2_b     = (const float*)d_in[4];
  const float* in_proj_w= (const float*)d_in[5];
  const float* conv_w   = (const float*)d_in[6];
  const float* conv_b   = (const float*)d_in[7];
  const float* x_proj_w = (const float*)d_in[8];
  const float* dt_w     = (const float*)d_in[9];
  const float* dt_b     = (const float*)d_in[10];
  const float* A_log    = (const float*)d_in[11];
  const float* Dp       = (const float*)d_in[12];
  const float* out_w    = (const float*)d_in[13];
  const float* ffg_w    = (const float*)d_in[14];
  const float* ffg_b    = (const float*)d_in[15];
  const float* ffp_w    = (const float*)d_in[16];
  const float* ffp_b    = (const float*)d_in[17];

  char* ws = (char*)d_ws;
  // bf16 buffers
  bf16* w_inproj = (bf16*)(ws + 0);          // 4096x1024
  bf16* w_xproj  = (bf16*)(ws + 8388608);    // 128x2048 (pad from 96)
  bf16* w_dt     = (bf16*)(ws + 8912896);    // 2048x64
  bf16* w_out    = (bf16*)(ws + 9175040);    // 1024x2048
  bf16* w_ffg    = (bf16*)(ws + 13369344);   // 2048x1024
  bf16* w_ffp    = (bf16*)(ws + 17563648);   // 1024x1024
  bf16* x1_b     = (bf16*)(ws + 19660800);   // 2048x1024 (reused: normed)
  bf16* xz_b     = (bf16*)(ws + 23855104);   // 2048x4096
  bf16* xc_b     = (bf16*)(ws + 40632320);   // 2048x2048
  bf16* dt16     = (bf16*)(ws + 49020928);   // 2048x64
  bf16* y_b      = (bf16*)(ws + 49283072);   // 2048x2048 (reused: g 2048x1024)
  // f32 buffers
  float* xc_f    = (float*)(ws + 57671680);  // 2048x2048
  float* xdbl_f  = (float*)(ws + 74448896);  // 2048x96
  float* delta_f = (float*)(ws + 75235328);  // 2048x2048 (reused: gv)
  float* x2_f    = (float*)(ws + 92012544);  // 2048x1024
  float* outp    = (float*)d_out;            // 2048x1024

  #define GRID1(n) dim3(((n)+255)/256)
  // weight converts
  cvt_kernel<<<GRID1(4096L*1024), 256, 0, stream>>>(in_proj_w, w_inproj, 4096L*1024, 1024, 1024, 4096);
  cvt_kernel<<<GRID1(128L*2048), 256, 0, stream>>>(x_proj_w,  w_xproj,  128L*2048, 2048, 2048, 96);
  cvt_kernel<<<GRID1(2048L*64),  256, 0, stream>>>(dt_w,      w_dt,     2048L*64,   64,   64, 2048);
  cvt_kernel<<<GRID1(1024L*2048),256, 0, stream>>>(out_w,     w_out,    1024L*2048, 2048, 2048, 1024);
  cvt_kernel<<<GRID1(2048L*1024),256, 0, stream>>>(ffg_w,     w_ffg,    2048L*1024, 1024, 1024, 2048);
  cvt_kernel<<<GRID1(1024L*1024),256, 0, stream>>>(ffp_w,     w_ffp,    1024L*1024, 1024, 1024, 1024);

  // 1) x1 = LN(x)
  ln_kernel<<<NROWS, 256, 0, stream>>>(x, n1_g, n1_b, x1_b);
  // 2) xz = x1 @ in_proj_w^T   [2048 x 4096]
  gemm_k<0><<<dim3(16,32), 256, 0, stream>>>((const short*)x1_b, (const short*)w_inproj,
      1024, 4096, nullptr, nullptr, nullptr, xz_b);
  // 3) xc = silu(causal_conv(x_in)+cb)
  conv_kernel<<<GRID1((long)NROWS*DI), 256, 0, stream>>>(xz_b, conv_w, conv_b, xc_f, xc_b);
  // 4) x_dbl = xc @ x_proj_w^T  [2048 x 96]
  gemm_k<0><<<dim3(16,1), 256, 0, stream>>>((const short*)xc_b, (const short*)w_xproj,
      2048, 96, nullptr, nullptr, xdbl_f, nullptr);
  // 5) dt16 = bf16(x_dbl[:, :64])
  cvt_kernel<<<GRID1(2048L*64), 256, 0, stream>>>(xdbl_f, dt16, 2048L*64, 64, 96, 2048);
  // 6) delta = softplus(dt @ dt_w^T + dt_b)  [2048 x 2048]
  gemm_k<1><<<dim3(16,16), 256, 0, stream>>>((const short*)dt16, (const short*)w_dt,
      64, 2048, dt_b, nullptr, delta_f, nullptr);
  // 7) scan -> y  (bf16), fused +xc*D and *silu(z)
  scan_kernel<<<256, 256, 0, stream>>>(delta_f, xc_f, xdbl_f, xz_b, A_log, Dp, y_b);
  // 8) x2 = x + y @ out_w^T  [2048 x 1024]
  gemm_k<0><<<dim3(16,8), 256, 0, stream>>>((const short*)y_b, (const short*)w_out,
      2048, 1024, nullptr, x, x2_f, nullptr);
  // 9) normed = LN(x2)  (reuse x1_b)
  ln_kernel<<<NROWS, 256, 0, stream>>>(x2_f, n2_g, n2_b, x1_b);
  // 10) gv = normed @ ffg_w^T + ffg_b  [2048 x 2048]  (reuse delta_f)
  gemm_k<0><<<dim3(16,16), 256, 0, stream>>>((const short*)x1_b, (const short*)w_ffg,
      1024, 2048, ffg_b, nullptr, delta_f, nullptr);
  // 11) g = silu(gate)*val -> bf16 (reuse y_b)
  gated_kernel<<<GRID1((long)NROWS*DM), 256, 0, stream>>>(delta_f, y_b);
  // 12) out = x2 + g @ ffp_w^T + ffp_b
  gemm_k<0><<<dim3(16,8), 256, 0, stream>>>((const short*)y_b, (const short*)w_ffp,
      1024, 1024, ffp_b, x2_f, outp, nullptr);
  #undef GRID1
}

// Round 2
// 641.527 us; speedup vs baseline: 1.3353x; 1.3353x over previous
//
#include <hip/hip_runtime.h>
#include <hip/hip_bf16.h>

#define DM 1024
#define DI 2048
#define LSEQ 1024
#define BSZ 2
#define NROWS (BSZ*LSEQ)   // 2048

typedef __attribute__((ext_vector_type(4))) float f32x4;
typedef __attribute__((ext_vector_type(8))) short bf16x8;
typedef __hip_bfloat16 bf16;

__device__ __forceinline__ float sigmoidf_(float x){ return 1.f/(1.f+__expf(-x)); }

// ---------------- f32 -> bf16 convert (optional row-pad / row-stride) ----------------
__global__ void cvt_kernel(const float* __restrict__ src, bf16* __restrict__ dst,
                           long n, int cols, int src_stride, int src_rows)
{
  long i = (long)blockIdx.x*blockDim.x + threadIdx.x;
  if (i >= n) return;
  int r = (int)(i / cols);
  int c = (int)(i - (long)r*cols);
  float v = (r < src_rows) ? src[(long)r*src_stride + c] : 0.f;
  dst[i] = __float2bfloat16(v);
}

// ---------------- LayerNorm (row=1024) f32 -> bf16 ----------------
__global__ __launch_bounds__(256) void ln_kernel(const float* __restrict__ x,
    const float* __restrict__ g, const float* __restrict__ b, bf16* __restrict__ out)
{
  int row = blockIdx.x;
  float4 v = ((const float4*)(x + (long)row*DM))[threadIdx.x];
  float s  = v.x+v.y+v.z+v.w;
  float s2 = v.x*v.x+v.y*v.y+v.z*v.z+v.w*v.w;
  #pragma unroll
  for (int m=32;m;m>>=1){ s += __shfl_xor(s,m); s2 += __shfl_xor(s2,m); }
  __shared__ float ws0[4], ws1[4];
  int wv = threadIdx.x>>6;
  if ((threadIdx.x&63)==0){ ws0[wv]=s; ws1[wv]=s2; }
  __syncthreads();
  s  = ws0[0]+ws0[1]+ws0[2]+ws0[3];
  s2 = ws1[0]+ws1[1]+ws1[2]+ws1[3];
  float mu  = s*(1.f/DM);
  float var = s2*(1.f/DM) - mu*mu;
  float rs  = rsqrtf(var + 1e-5f);
  int c = threadIdx.x*4;
  float4 gg = ((const float4*)g)[threadIdx.x];
  float4 bb = ((const float4*)b)[threadIdx.x];
  bf16* o = out + (long)row*DM + c;
  o[0] = __float2bfloat16((v.x-mu)*rs*gg.x + bb.x);
  o[1] = __float2bfloat16((v.y-mu)*rs*gg.y + bb.y);
  o[2] = __float2bfloat16((v.z-mu)*rs*gg.z + bb.z);
  o[3] = __float2bfloat16((v.w-mu)*rs*gg.w + bb.w);
}

// ---------------- bf16 MFMA GEMM: C[M,N] = A[M,K] @ B[N,K]^T (+bias)(+act)(+res) ----
// 128x128 tile, 256 threads (4 waves), each wave 64x64 via 4x4 frags of 16x16x32.
// ACT: 0=none, 1=softplus. blockIdx.z = K-split index (A,B advance z*K; outf by z*pstride).
template<int ACT>
__global__ __launch_bounds__(256)
void gemm_k(const short* __restrict__ A, int lda, const short* __restrict__ B, int ldb,
            int K, int Nreal, int ldo, int pstride,
            const float* __restrict__ bias, const float* __restrict__ res,
            float* __restrict__ outf, bf16* __restrict__ outb)
{
  A += (size_t)blockIdx.z * K;
  B += (size_t)blockIdx.z * K;
  if (outf) outf += (size_t)blockIdx.z * pstride;

  __shared__ short As[128*32];
  __shared__ short Bs[128*32];
  const int tid  = threadIdx.x;
  const int wave = tid>>6, lane = tid&63;
  const int m0 = blockIdx.x*128, n0 = blockIdx.y*128;
  const int wm = (wave>>1)*64, wn = (wave&1)*64;
  const int lr = lane&15, lk = lane>>4;

  f32x4 acc[4][4];
  #pragma unroll
  for (int i=0;i<4;i++)
    #pragma unroll
    for (int j=0;j<4;j++) acc[i][j] = f32x4{0.f,0.f,0.f,0.f};

  const int r0 = tid>>2;        // 0..63
  const int kb = (tid&3)*8;     // 0,8,16,24 (bf16 elems)

  for (int kt=0; kt<K; kt+=32) {
    #pragma unroll
    for (int i=0;i<2;i++){
      int row = r0 + i*64;
      __builtin_amdgcn_global_load_lds(
        (const __attribute__((address_space(1))) void*)(A + (size_t)(m0+row)*lda + kt + kb),
        (__attribute__((address_space(3))) void*)(As + row*32 + kb), 16, 0, 0);
    }
    #pragma unroll
    for (int i=0;i<2;i++){
      int row = r0 + i*64;
      __builtin_amdgcn_global_load_lds(
        (const __attribute__((address_space(1))) void*)(B + (size_t)(n0+row)*ldb + kt + kb),
        (__attribute__((address_space(3))) void*)(Bs + row*32 + kb), 16, 0, 0);
    }
    asm volatile("s_waitcnt vmcnt(0)");
    __syncthreads();
    bf16x8 af[4], bfr[4];
    #pragma unroll
    for (int i=0;i<4;i++) af[i]  = *(const bf16x8*)(As + (wm+i*16+lr)*32 + lk*8);
    #pragma unroll
    for (int j=0;j<4;j++) bfr[j] = *(const bf16x8*)(Bs + (wn+j*16+lr)*32 + lk*8);
    #pragma unroll
    for (int i=0;i<4;i++)
      #pragma unroll
      for (int j=0;j<4;j++)
        acc[i][j] = __builtin_amdgcn_mfma_f32_16x16x32_bf16(af[i], bfr[j], acc[i][j], 0,0,0);
    __syncthreads();
  }

  // epilogue: C/D map col=lane&15, row=(lane>>4)*4+reg   [m89-verified]
  #pragma unroll
  for (int i=0;i<4;i++){
    #pragma unroll
    for (int j=0;j<4;j++){
      int col = n0 + wn + j*16 + lr;
      if (col >= Nreal) continue;
      #pragma unroll
      for (int r=0;r<4;r++){
        int row = m0 + wm + i*16 + lk*4 + r;
        float v = acc[i][j][r];
        if (bias) v += bias[col];
        if (ACT==1) v = (v > 20.f) ? v : log1pf(__expf(v));
        if (res)  v += res[(size_t)row*ldo + col];
        if (outf) outf[(size_t)row*ldo + col] = v;
        if (outb) outb[(size_t)row*ldo + col] = __float2bfloat16(v);
      }
    }
  }
}

// ---------------- split-K reduce for x_proj; fuses dt bf16 slice --------------------
__global__ __launch_bounds__(256) void xproj_reduce(const float* __restrict__ part,
    float* __restrict__ xdbl, bf16* __restrict__ dt16)
{
  int i = blockIdx.x*256 + threadIdx.x;
  if (i >= NROWS*96) return;
  float s = 0.f;
  #pragma unroll
  for (int k=0;k<8;k++) s += part[(long)k*(NROWS*96) + i];
  xdbl[i] = s;
  int r = i/96, c = i - r*96;
  if (c < 64) dt16[r*64 + c] = __float2bfloat16(s);
}

// ---------------- depthwise causal conv(4) + silu; writes f32 + bf16 ----------------
__global__ __launch_bounds__(256) void conv_kernel(const bf16* __restrict__ xz,
    const float* __restrict__ w, const float* __restrict__ cb,
    float* __restrict__ xcf, bf16* __restrict__ xcb)
{
  long i = (long)blockIdx.x*blockDim.x + threadIdx.x;  // NROWS*DI
  int d  = (int)(i & (DI-1));
  int bl = (int)(i >> 11);
  int l  = bl & (LSEQ-1);
  int b  = bl >> 10;
  float acc = cb[d];
  #pragma unroll
  for (int k=0;k<4;k++){
    int ls = l-3+k;
    if (ls >= 0)
      acc += __bfloat162float(xz[(long)(b*LSEQ+ls)*(2*DI) + d]) * w[d*4+k];
  }
  float s = acc * sigmoidf_(acc);
  xcf[i] = s;
  xcb[i] = __float2bfloat16(s);
}

// ======================= chunked SSM scan: 16 chunks of 64 ==========================
// recurrence per (b,d,n): h = a*h + u, a=exp(delta*Aneg), u=delta*B*xc
// phase1: per-chunk carries (P=prod a, S=scan from 0)
__global__ __launch_bounds__(256) void scan_p1(
    const float* __restrict__ delta, const float* __restrict__ xc,
    const float* __restrict__ xdbl, const float* __restrict__ A_log,
    float* __restrict__ carP, float* __restrict__ carS)
{
  int d0 = blockIdx.x*16, c = blockIdx.y, b = blockIdx.z;
  int t = threadIdx.x, dl = t>>4, n = t&15;
  float Aneg = -__expf(A_log[d0*16 + t]);   // = A_log[(d0+dl)*16+n]
  __shared__ float sD[64][16], sX[64][16], sB[64][16];
  long rbase = (long)(b*LSEQ + c*64);
  #pragma unroll
  for (int i=0;i<4;i++){
    int ll = (t>>4) + i*16, dd = t&15;
    long row = rbase + ll;
    sD[ll][dd] = delta[row*DI + d0+dd];
    sX[ll][dd] = xc[row*DI + d0+dd];
    sB[ll][dd] = xdbl[row*96 + 64 + dd];
  }
  __syncthreads();
  float h = 0.f, P = 1.f;
  #pragma unroll 4
  for (int ll=0; ll<64; ll++){
    float du = sD[ll][dl];
    float a = __expf(du*Aneg);
    h = a*h + du*sX[ll][dl]*sB[ll][n];
    P *= a;
  }
  int idx = ((c*2+b)*2048 + d0)*16 + t;
  carP[idx] = P; carS[idx] = h;
}

// phase2: compose carries over 16 chunks -> per-chunk initial state h_in
__global__ __launch_bounds__(256) void scan_p2(const float* __restrict__ carP,
    const float* __restrict__ carS, float* __restrict__ hin)
{
  int tid = blockIdx.x*256 + threadIdx.x;   // 65536 = 2*2048*16
  int b = tid>>15, lo = tid & 32767;
  float h = 0.f;
  #pragma unroll
  for (int c=0;c<16;c++){
    int idx = ((c*2+b)<<15) + lo;
    hin[idx] = h;
    h = carS[idx] + carP[idx]*h;
  }
}

// phase3: within-chunk scan from h_in, with fused y = (sum_n h*C + xc*D)*silu(z)
__global__ __launch_bounds__(256) void scan_p3(
    const float* __restrict__ delta, const float* __restrict__ xc,
    const float* __restrict__ xdbl, const bf16* __restrict__ xz,
    const float* __restrict__ A_log, const float* __restrict__ Dp,
    const float* __restrict__ hin, bf16* __restrict__ y)
{
  int d0 = blockIdx.x*16, c = blockIdx.y, b = blockIdx.z;
  int t = threadIdx.x, dl = t>>4, n = t&15;
  int d = d0 + dl;
  float Aneg = -__expf(A_log[d0*16 + t]);
  float Dd = Dp[d];
  __shared__ float sD[64][16], sX[64][16], sB[64][16], sC[64][16], sZ[64][16];
  long rbase = (long)(b*LSEQ + c*64);
  #pragma unroll
  for (int i=0;i<4;i++){
    int ll = (t>>4) + i*16, dd = t&15;
    long row = rbase + ll;
    sD[ll][dd] = delta[row*DI + d0+dd];
    sX[ll][dd] = xc[row*DI + d0+dd];
    sB[ll][dd] = xdbl[row*96 + 64 + dd];
    sC[ll][dd] = xdbl[row*96 + 80 + dd];
    sZ[ll][dd] = __bfloat162float(xz[row*(2*DI) + DI + d0+dd]);
  }
  __syncthreads();
  float h = hin[((c*2+b)*2048 + d0)*16 + t];
  #pragma unroll 4
  for (int ll=0; ll<64; ll++){
    float du = sD[ll][dl], xv = sX[ll][dl];
    float a = __expf(du*Aneg);
    h = a*h + du*xv*sB[ll][n];
    float r = h*sC[ll][n];
    r += __shfl_xor(r,8); r += __shfl_xor(r,4);
    r += __shfl_xor(r,2); r += __shfl_xor(r,1);
    if (n==0){
      float z = sZ[ll][dl];
      y[(rbase+ll)*DI + d] = __float2bfloat16((r + xv*Dd)*(z*sigmoidf_(z)));
    }
  }
}

// ---------------- gated: g = silu(gv[:, :1024]) * gv[:, 1024:] -> bf16 -------------
__global__ __launch_bounds__(256) void gated_kernel(const float* __restrict__ gv,
                                                    bf16* __restrict__ g)
{
  long i = (long)blockIdx.x*blockDim.x + threadIdx.x;  // NROWS*DM
  int r = (int)(i >> 10);
  int c = (int)(i & (DM-1));
  float gt = gv[(long)r*(2*DM) + c];
  float vl = gv[(long)r*(2*DM) + DM + c];
  g[i] = __float2bfloat16(gt * sigmoidf_(gt) * vl);
}

// ------------------------------- launcher ------------------------------------------
extern "C" void kernel_launch(void* const* d_in, const int* in_sizes, int n_in,
                              void* d_out, int out_size, void* d_ws, size_t ws_size,
                              hipStream_t stream)
{
  const float* x        = (const float*)d_in[0];
  const float* n1_g     = (const float*)d_in[1];
  const float* n1_b     = (const float*)d_in[2];
  const float* n2_g     = (const float*)d_in[3];
  const float* n2_b     = (const float*)d_in[4];
  const float* in_proj_w= (const float*)d_in[5];
  const float* conv_w   = (const float*)d_in[6];
  const float* conv_b   = (const float*)d_in[7];
  const float* x_proj_w = (const float*)d_in[8];
  const float* dt_w     = (const float*)d_in[9];
  const float* dt_b     = (const float*)d_in[10];
  const float* A_log    = (const float*)d_in[11];
  const float* Dp       = (const float*)d_in[12];
  const float* out_w    = (const float*)d_in[13];
  const float* ffg_w    = (const float*)d_in[14];
  const float* ffg_b    = (const float*)d_in[15];
  const float* ffp_w    = (const float*)d_in[16];
  const float* ffp_b    = (const float*)d_in[17];

  char* ws = (char*)d_ws;
  // bf16 buffers
  bf16* w_inproj = (bf16*)(ws + 0);          // 4096x1024
  bf16* w_xproj  = (bf16*)(ws + 8388608);    // 128x2048 (zero-pad from 96 rows)
  bf16* w_dt     = (bf16*)(ws + 8912896);    // 2048x64
  bf16* w_out    = (bf16*)(ws + 9175040);    // 1024x2048
  bf16* w_ffg    = (bf16*)(ws + 13369344);   // 2048x1024
  bf16* w_ffp    = (bf16*)(ws + 17563648);   // 1024x1024
  bf16* x1_b     = (bf16*)(ws + 19660800);   // 2048x1024 (reused: normed)
  bf16* xz_b     = (bf16*)(ws + 23855104);   // 2048x4096
  bf16* xc_b     = (bf16*)(ws + 40632320);   // 2048x2048 (dead after x_proj ->
  float* carP    = (float*)(ws + 40632320);  //   reused: carries P [16][2][2048][16]/2)
  float* carS    = (float*)(ws + 44826624);  //   carries S (second 4MB of xc_b)
  bf16* dt16     = (bf16*)(ws + 49020928);   // 2048x64
  bf16* y_b      = (bf16*)(ws + 49283072);   // 2048x2048 (reused: g 2048x1024)
  // f32 buffers
  float* xc_f    = (float*)(ws + 57671680);  // 2048x2048
  float* xdbl_f  = (float*)(ws + 74448896);  // 2048x96
  float* delta_f = (float*)(ws + 75235328);  // 2048x2048 (pre-used: x_proj partials; reused: gv)
  float* part_xp = (float*)(ws + 75235328);  // 8x2048x96 partials (dead before delta write)
  float* x2_f    = (float*)(ws + 92012544);  // 2048x1024 (first 4MB pre-used as hin)
  float* hin     = (float*)(ws + 92012544);  // 2*2048*16*16 (dead before x2 write)
  float* outp    = (float*)d_out;            // 2048x1024

  #define GRID1(n) dim3((int)(((n)+255)/256))
  // weight converts
  cvt_kernel<<<GRID1(4096L*1024), 256, 0, stream>>>(in_proj_w, w_inproj, 4096L*1024, 1024, 1024, 4096);
  cvt_kernel<<<GRID1(128L*2048), 256, 0, stream>>>(x_proj_w,  w_xproj,  128L*2048, 2048, 2048, 96);
  cvt_kernel<<<GRID1(2048L*64),  256, 0, stream>>>(dt_w,      w_dt,     2048L*64,   64,   64, 2048);
  cvt_kernel<<<GRID1(1024L*2048),256, 0, stream>>>(out_w,     w_out,    1024L*2048, 2048, 2048, 1024);
  cvt_kernel<<<GRID1(2048L*1024),256, 0, stream>>>(ffg_w,     w_ffg,    2048L*1024, 1024, 1024, 2048);
  cvt_kernel<<<GRID1(1024L*1024),256, 0, stream>>>(ffp_w,     w_ffp,    1024L*1024, 1024, 1024, 1024);

  // 1) x1 = LN(x)
  ln_kernel<<<NROWS, 256, 0, stream>>>(x, n1_g, n1_b, x1_b);
  // 2) xz = x1 @ in_proj_w^T   [2048 x 4096]
  gemm_k<0><<<dim3(16,32), 256, 0, stream>>>((const short*)x1_b, 1024, (const short*)w_inproj, 1024,
      1024, 4096, 4096, 0, nullptr, nullptr, nullptr, xz_b);
  // 3) xc = silu(causal_conv(x_in)+cb)
  conv_kernel<<<GRID1((long)NROWS*DI), 256, 0, stream>>>(xz_b, conv_w, conv_b, xc_f, xc_b);
  // 4) x_dbl partials = xc @ x_proj_w^T  [2048 x 96], split-K 8x256
  gemm_k<0><<<dim3(16,1,8), 256, 0, stream>>>((const short*)xc_b, 2048, (const short*)w_xproj, 2048,
      256, 96, 96, NROWS*96, nullptr, nullptr, part_xp, nullptr);
  // 5) reduce partials -> xdbl_f (+ dt16 bf16 slice)
  xproj_reduce<<<GRID1((long)NROWS*96), 256, 0, stream>>>(part_xp, xdbl_f, dt16);
  // 6) delta = softplus(dt @ dt_w^T + dt_b)  [2048 x 2048]
  gemm_k<1><<<dim3(16,16), 256, 0, stream>>>((const short*)dt16, 64, (const short*)w_dt, 64,
      64, 2048, 2048, 0, dt_b, nullptr, delta_f, nullptr);
  // 7) chunked scan -> y (bf16), fused +xc*D and *silu(z)
  scan_p1<<<dim3(128,16,2), 256, 0, stream>>>(delta_f, xc_f, xdbl_f, A_log, carP, carS);
  scan_p2<<<dim3(256), 256, 0, stream>>>(carP, carS, hin);
  scan_p3<<<dim3(128,16,2), 256, 0, stream>>>(delta_f, xc_f, xdbl_f, xz_b, A_log, Dp, hin, y_b);
  // 8) x2 = x + y @ out_w^T  [2048 x 1024]
  gemm_k<0><<<dim3(16,8), 256, 0, stream>>>((const short*)y_b, 2048, (const short*)w_out, 2048,
      2048, 1024, 1024, 0, nullptr, x, x2_f, nullptr);
  // 9) normed = LN(x2)  (reuse x1_b)
  ln_kernel<<<NROWS, 256, 0, stream>>>(x2_f, n2_g, n2_b, x1_b);
  // 10) gv = normed @ ffg_w^T + ffg_b  [2048 x 2048]  (reuse delta_f)
  gemm_k<0><<<dim3(16,16), 256, 0, stream>>>((const short*)x1_b, 1024, (const short*)w_ffg, 1024,
      1024, 2048, 2048, 0, ffg_b, nullptr, delta_f, nullptr);
  // 11) g = silu(gate)*val -> bf16 (reuse y_b)
  gated_kernel<<<GRID1((long)NROWS*DM), 256, 0, stream>>>(delta_f, y_b);
  // 12) out = x2 + g @ ffp_w^T + ffp_b
  gemm_k<0><<<dim3(16,8), 256, 0, stream>>>((const short*)y_b, 1024, (const short*)w_ffp, 1024,
      1024, 1024, 1024, 0, ffp_b, x2_f, outp, nullptr);
  #undef GRID1
}

// Round 3
// 485.614 us; speedup vs baseline: 1.7640x; 1.3211x over previous
//
#include <hip/hip_runtime.h>
#include <hip/hip_bf16.h>

#define DM 1024
#define DI 2048
#define LSEQ 1024
#define BSZ 2
#define NROWS (BSZ*LSEQ)   // 2048

typedef __attribute__((ext_vector_type(4))) float f32x4;
typedef __attribute__((ext_vector_type(8))) short bf16x8;
typedef __hip_bfloat16 bf16;

__device__ __forceinline__ float sigmoidf_(float x){ return 1.f/(1.f+__expf(-x)); }

// ---------------- f32 -> bf16 convert (optional row-pad / row-stride) ----------------
__global__ void cvt_kernel(const float* __restrict__ src, bf16* __restrict__ dst,
                           long n, int cols, int src_stride, int src_rows)
{
  long i = (long)blockIdx.x*blockDim.x + threadIdx.x;
  if (i >= n) return;
  int r = (int)(i / cols);
  int c = (int)(i - (long)r*cols);
  float v = (r < src_rows) ? src[(long)r*src_stride + c] : 0.f;
  dst[i] = __float2bfloat16(v);
}

// ---------------- LayerNorm (row=1024) f32 -> bf16 ----------------
__global__ __launch_bounds__(256) void ln_kernel(const float* __restrict__ x,
    const float* __restrict__ g, const float* __restrict__ b, bf16* __restrict__ out)
{
  int row = blockIdx.x;
  float4 v = ((const float4*)(x + (long)row*DM))[threadIdx.x];
  float s  = v.x+v.y+v.z+v.w;
  float s2 = v.x*v.x+v.y*v.y+v.z*v.z+v.w*v.w;
  #pragma unroll
  for (int m=32;m;m>>=1){ s += __shfl_xor(s,m); s2 += __shfl_xor(s2,m); }
  __shared__ float ws0[4], ws1[4];
  int wv = threadIdx.x>>6;
  if ((threadIdx.x&63)==0){ ws0[wv]=s; ws1[wv]=s2; }
  __syncthreads();
  s  = ws0[0]+ws0[1]+ws0[2]+ws0[3];
  s2 = ws1[0]+ws1[1]+ws1[2]+ws1[3];
  float mu  = s*(1.f/DM);
  float var = s2*(1.f/DM) - mu*mu;
  float rs  = rsqrtf(var + 1e-5f);
  int c = threadIdx.x*4;
  float4 gg = ((const float4*)g)[threadIdx.x];
  float4 bb = ((const float4*)b)[threadIdx.x];
  bf16* o = out + (long)row*DM + c;
  o[0] = __float2bfloat16((v.x-mu)*rs*gg.x + bb.x);
  o[1] = __float2bfloat16((v.y-mu)*rs*gg.y + bb.y);
  o[2] = __float2bfloat16((v.z-mu)*rs*gg.z + bb.z);
  o[3] = __float2bfloat16((v.w-mu)*rs*gg.w + bb.w);
}

// ---------------- bf16 MFMA GEMM: C[M,N] = A[M,K] @ B[N,K]^T (+bias)(+act)(+res) ----
// 128x128 tile, 256 threads (4 waves), each wave 64x64 via 4x4 frags of 16x16x32.
// ACT: 0=none, 1=softplus (fast: v_exp + v_log, NOT libm log1pf — 147us -> ~10us)
template<int ACT>
__global__ __launch_bounds__(256)
void gemm_k(const short* __restrict__ A, int lda, const short* __restrict__ B, int ldb,
            int K, int Nreal, int ldo, int pstride,
            const float* __restrict__ bias, const float* __restrict__ res,
            float* __restrict__ outf, bf16* __restrict__ outb)
{
  A += (size_t)blockIdx.z * K;
  B += (size_t)blockIdx.z * K;
  if (outf) outf += (size_t)blockIdx.z * pstride;

  __shared__ short As[128*32];
  __shared__ short Bs[128*32];
  const int tid  = threadIdx.x;
  const int wave = tid>>6, lane = tid&63;
  const int m0 = blockIdx.x*128, n0 = blockIdx.y*128;
  const int wm = (wave>>1)*64, wn = (wave&1)*64;
  const int lr = lane&15, lk = lane>>4;

  f32x4 acc[4][4];
  #pragma unroll
  for (int i=0;i<4;i++)
    #pragma unroll
    for (int j=0;j<4;j++) acc[i][j] = f32x4{0.f,0.f,0.f,0.f};

  const int r0 = tid>>2;        // 0..63
  const int kb = (tid&3)*8;     // 0,8,16,24 (bf16 elems)

  for (int kt=0; kt<K; kt+=32) {
    #pragma unroll
    for (int i=0;i<2;i++){
      int row = r0 + i*64;
      __builtin_amdgcn_global_load_lds(
        (const __attribute__((address_space(1))) void*)(A + (size_t)(m0+row)*lda + kt + kb),
        (__attribute__((address_space(3))) void*)(As + row*32 + kb), 16, 0, 0);
    }
    #pragma unroll
    for (int i=0;i<2;i++){
      int row = r0 + i*64;
      __builtin_amdgcn_global_load_lds(
        (const __attribute__((address_space(1))) void*)(B + (size_t)(n0+row)*ldb + kt + kb),
        (__attribute__((address_space(3))) void*)(Bs + row*32 + kb), 16, 0, 0);
    }
    asm volatile("s_waitcnt vmcnt(0)");
    __syncthreads();
    bf16x8 af[4], bfr[4];
    #pragma unroll
    for (int i=0;i<4;i++) af[i]  = *(const bf16x8*)(As + (wm+i*16+lr)*32 + lk*8);
    #pragma unroll
    for (int j=0;j<4;j++) bfr[j] = *(const bf16x8*)(Bs + (wn+j*16+lr)*32 + lk*8);
    #pragma unroll
    for (int i=0;i<4;i++)
      #pragma unroll
      for (int j=0;j<4;j++)
        acc[i][j] = __builtin_amdgcn_mfma_f32_16x16x32_bf16(af[i], bfr[j], acc[i][j], 0,0,0);
    __syncthreads();
  }

  // epilogue: C/D map col=lane&15, row=(lane>>4)*4+reg   [m89-verified]
  #pragma unroll
  for (int i=0;i<4;i++){
    #pragma unroll
    for (int j=0;j<4;j++){
      int col = n0 + wn + j*16 + lr;
      if (col >= Nreal) continue;
      #pragma unroll
      for (int r=0;r<4;r++){
        int row = m0 + wm + i*16 + lk*4 + r;
        float v = acc[i][j][r];
        if (bias) v += bias[col];
        if (ACT==1){
          float ev = __expf(v);
          v = (v > 20.f) ? v : __logf(1.f + ev);
        }
        if (res)  v += res[(size_t)row*ldo + col];
        if (outf) outf[(size_t)row*ldo + col] = v;
        if (outb) outb[(size_t)row*ldo + col] = __float2bfloat16(v);
      }
    }
  }
}

// ---------------- split-K reduce for x_proj; fuses dt bf16 slice --------------------
__global__ __launch_bounds__(256) void xproj_reduce(const float* __restrict__ part,
    float* __restrict__ xdbl, bf16* __restrict__ dt16)
{
  int i = blockIdx.x*256 + threadIdx.x;
  if (i >= NROWS*96) return;
  float s = 0.f;
  #pragma unroll
  for (int k=0;k<8;k++) s += part[(long)k*(NROWS*96) + i];
  xdbl[i] = s;
  int r = i/96, c = i - r*96;
  if (c < 64) dt16[r*64 + c] = __float2bfloat16(s);
}

// ---------------- depthwise causal conv(4) + silu; writes f32 + bf16 ----------------
__global__ __launch_bounds__(256) void conv_kernel(const bf16* __restrict__ xz,
    const float* __restrict__ w, const float* __restrict__ cb,
    float* __restrict__ xcf, bf16* __restrict__ xcb)
{
  long i = (long)blockIdx.x*blockDim.x + threadIdx.x;  // NROWS*DI
  int d  = (int)(i & (DI-1));
  int bl = (int)(i >> 11);
  int l  = bl & (LSEQ-1);
  int b  = bl >> 10;
  float acc = cb[d];
  #pragma unroll
  for (int k=0;k<4;k++){
    int ls = l-3+k;
    if (ls >= 0)
      acc += __bfloat162float(xz[(long)(b*LSEQ+ls)*(2*DI) + d]) * w[d*4+k];
  }
  float s = acc * sigmoidf_(acc);
  xcf[i] = s;
  xcb[i] = __float2bfloat16(s);
}

// ======================= chunked SSM scan: 16 chunks of 64 ==========================
// recurrence per (b,d,n): h = a*h + u, a=exp(delta*Aneg), u=delta*B*xc
// phase1: per-chunk carries (P=prod a, S=scan from 0)
__global__ __launch_bounds__(256) void scan_p1(
    const float* __restrict__ delta, const float* __restrict__ xc,
    const float* __restrict__ xdbl, const float* __restrict__ A_log,
    float* __restrict__ carP, float* __restrict__ carS)
{
  int d0 = blockIdx.x*16, c = blockIdx.y, b = blockIdx.z;
  int t = threadIdx.x, dl = t>>4, n = t&15;
  float Aneg = -__expf(A_log[d0*16 + t]);   // = A_log[(d0+dl)*16+n]
  __shared__ float sD[64][16], sX[64][16], sB[64][16];
  long rbase = (long)(b*LSEQ + c*64);
  #pragma unroll
  for (int i=0;i<4;i++){
    int ll = (t>>4) + i*16, dd = t&15;
    long row = rbase + ll;
    sD[ll][dd] = delta[row*DI + d0+dd];
    sX[ll][dd] = xc[row*DI + d0+dd];
    sB[ll][dd] = xdbl[row*96 + 64 + dd];
  }
  __syncthreads();
  float h = 0.f, P = 1.f;
  #pragma unroll 4
  for (int ll=0; ll<64; ll++){
    float du = sD[ll][dl];
    float a = __expf(du*Aneg);
    h = a*h + du*sX[ll][dl]*sB[ll][n];
    P *= a;
  }
  int idx = ((c*2+b)*2048 + d0)*16 + t;
  carP[idx] = P; carS[idx] = h;
}

// phase2: compose carries over 16 chunks -> per-chunk initial state h_in
__global__ __launch_bounds__(256) void scan_p2(const float* __restrict__ carP,
    const float* __restrict__ carS, float* __restrict__ hin)
{
  int tid = blockIdx.x*256 + threadIdx.x;   // 65536 = 2*2048*16
  int b = tid>>15, lo = tid & 32767;
  float h = 0.f;
  #pragma unroll
  for (int c=0;c<16;c++){
    int idx = ((c*2+b)<<15) + lo;
    hin[idx] = h;
    h = carS[idx] + carP[idx]*h;
  }
}

// phase3: within-chunk scan from h_in, with fused y = (sum_n h*C + xc*D)*silu(z)
__global__ __launch_bounds__(256) void scan_p3(
    const float* __restrict__ delta, const float* __restrict__ xc,
    const float* __restrict__ xdbl, const bf16* __restrict__ xz,
    const float* __restrict__ A_log, const float* __restrict__ Dp,
    const float* __restrict__ hin, bf16* __restrict__ y)
{
  int d0 = blockIdx.x*16, c = blockIdx.y, b = blockIdx.z;
  int t = threadIdx.x, dl = t>>4, n = t&15;
  int d = d0 + dl;
  float Aneg = -__expf(A_log[d0*16 + t]);
  float Dd = Dp[d];
  __shared__ float sD[64][16], sX[64][16], sB[64][16], sC[64][16], sZ[64][16];
  long rbase = (long)(b*LSEQ + c*64);
  #pragma unroll
  for (int i=0;i<4;i++){
    int ll = (t>>4) + i*16, dd = t&15;
    long row = rbase + ll;
    sD[ll][dd] = delta[row*DI + d0+dd];
    sX[ll][dd] = xc[row*DI + d0+dd];
    sB[ll][dd] = xdbl[row*96 + 64 + dd];
    sC[ll][dd] = xdbl[row*96 + 80 + dd];
    sZ[ll][dd] = __bfloat162float(xz[row*(2*DI) + DI + d0+dd]);
  }
  __syncthreads();
  float h = hin[((c*2+b)*2048 + d0)*16 + t];
  #pragma unroll 4
  for (int ll=0; ll<64; ll++){
    float du = sD[ll][dl], xv = sX[ll][dl];
    float a = __expf(du*Aneg);
    h = a*h + du*xv*sB[ll][n];
    float r = h*sC[ll][n];
    r += __shfl_xor(r,8); r += __shfl_xor(r,4);
    r += __shfl_xor(r,2); r += __shfl_xor(r,1);
    if (n==0){
      float z = sZ[ll][dl];
      y[(rbase+ll)*DI + d] = __float2bfloat16((r + xv*Dd)*(z*sigmoidf_(z)));
    }
  }
}

// ---------------- gated: g = silu(gv[:, :1024]) * gv[:, 1024:] -> bf16 -------------
__global__ __launch_bounds__(256) void gated_kernel(const float* __restrict__ gv,
                                                    bf16* __restrict__ g)
{
  long i = (long)blockIdx.x*blockDim.x + threadIdx.x;  // NROWS*DM
  int r = (int)(i >> 10);
  int c = (int)(i & (DM-1));
  float gt = gv[(long)r*(2*DM) + c];
  float vl = gv[(long)r*(2*DM) + DM + c];
  g[i] = __float2bfloat16(gt * sigmoidf_(gt) * vl);
}

// ------------------------------- launcher ------------------------------------------
extern "C" void kernel_launch(void* const* d_in, const int* in_sizes, int n_in,
                              void* d_out, int out_size, void* d_ws, size_t ws_size,
                              hipStream_t stream)
{
  const float* x        = (const float*)d_in[0];
  const float* n1_g     = (const float*)d_in[1];
  const float* n1_b     = (const float*)d_in[2];
  const float* n2_g     = (const float*)d_in[3];
  const float* n2_b     = (const float*)d_in[4];
  const float* in_proj_w= (const float*)d_in[5];
  const float* conv_w   = (const float*)d_in[6];
  const float* conv_b   = (const float*)d_in[7];
  const float* x_proj_w = (const float*)d_in[8];
  const float* dt_w     = (const float*)d_in[9];
  const float* dt_b     = (const float*)d_in[10];
  const float* A_log    = (const float*)d_in[11];
  const float* Dp       = (const float*)d_in[12];
  const float* out_w    = (const float*)d_in[13];
  const float* ffg_w    = (const float*)d_in[14];
  const float* ffg_b    = (const float*)d_in[15];
  const float* ffp_w    = (const float*)d_in[16];
  const float* ffp_b    = (const float*)d_in[17];

  char* ws = (char*)d_ws;
  // bf16 buffers
  bf16* w_inproj = (bf16*)(ws + 0);          // 4096x1024
  bf16* w_xproj  = (bf16*)(ws + 8388608);    // 128x2048 (zero-pad from 96 rows)
  bf16* w_dt     = (bf16*)(ws + 8912896);    // 2048x64
  bf16* w_out    = (bf16*)(ws + 9175040);    // 1024x2048
  bf16* w_ffg    = (bf16*)(ws + 13369344);   // 2048x1024
  bf16* w_ffp    = (bf16*)(ws + 17563648);   // 1024x1024
  bf16* x1_b     = (bf16*)(ws + 19660800);   // 2048x1024 (reused: normed)
  bf16* xz_b     = (bf16*)(ws + 23855104);   // 2048x4096
  bf16* xc_b     = (bf16*)(ws + 40632320);   // 2048x2048 (dead after x_proj ->
  float* carP    = (float*)(ws + 40632320);  //   reused: carries P [16][2][2048][16]/2)
  float* carS    = (float*)(ws + 44826624);  //   carries S (second 4MB of xc_b)
  bf16* dt16     = (bf16*)(ws + 49020928);   // 2048x64
  bf16* y_b      = (bf16*)(ws + 49283072);   // 2048x2048 (reused: g 2048x1024)
  // f32 buffers
  float* xc_f    = (float*)(ws + 57671680);  // 2048x2048
  float* xdbl_f  = (float*)(ws + 74448896);  // 2048x96
  float* delta_f = (float*)(ws + 75235328);  // 2048x2048 (pre-used: x_proj partials; reused: gv)
  float* part_xp = (float*)(ws + 75235328);  // 8x2048x96 partials (dead before delta write)
  float* x2_f    = (float*)(ws + 92012544);  // 2048x1024 (first 4MB pre-used as hin)
  float* hin     = (float*)(ws + 92012544);  // 2*2048*16*16 (dead before x2 write)
  float* outp    = (float*)d_out;            // 2048x1024

  #define GRID1(n) dim3((int)(((n)+255)/256))
  // weight converts
  cvt_kernel<<<GRID1(4096L*1024), 256, 0, stream>>>(in_proj_w, w_inproj, 4096L*1024, 1024, 1024, 4096);
  cvt_kernel<<<GRID1(128L*2048), 256, 0, stream>>>(x_proj_w,  w_xproj,  128L*2048, 2048, 2048, 96);
  cvt_kernel<<<GRID1(2048L*64),  256, 0, stream>>>(dt_w,      w_dt,     2048L*64,   64,   64, 2048);
  cvt_kernel<<<GRID1(1024L*2048),256, 0, stream>>>(out_w,     w_out,    1024L*2048, 2048, 2048, 1024);
  cvt_kernel<<<GRID1(2048L*1024),256, 0, stream>>>(ffg_w,     w_ffg,    2048L*1024, 1024, 1024, 2048);
  cvt_kernel<<<GRID1(1024L*1024),256, 0, stream>>>(ffp_w,     w_ffp,    1024L*1024, 1024, 1024, 1024);

  // 1) x1 = LN(x)
  ln_kernel<<<NROWS, 256, 0, stream>>>(x, n1_g, n1_b, x1_b);
  // 2) xz = x1 @ in_proj_w^T   [2048 x 4096]
  gemm_k<0><<<dim3(16,32), 256, 0, stream>>>((const short*)x1_b, 1024, (const short*)w_inproj, 1024,
      1024, 4096, 4096, 0, nullptr, nullptr, nullptr, xz_b);
  // 3) xc = silu(causal_conv(x_in)+cb)
  conv_kernel<<<GRID1((long)NROWS*DI), 256, 0, stream>>>(xz_b, conv_w, conv_b, xc_f, xc_b);
  // 4) x_dbl partials = xc @ x_proj_w^T  [2048 x 96], split-K 8x256
  gemm_k<0><<<dim3(16,1,8), 256, 0, stream>>>((const short*)xc_b, 2048, (const short*)w_xproj, 2048,
      256, 96, 96, NROWS*96, nullptr, nullptr, part_xp, nullptr);
  // 5) reduce partials -> xdbl_f (+ dt16 bf16 slice)
  xproj_reduce<<<GRID1((long)NROWS*96), 256, 0, stream>>>(part_xp, xdbl_f, dt16);
  // 6) delta = softplus(dt @ dt_w^T + dt_b)  [2048 x 2048]
  gemm_k<1><<<dim3(16,16), 256, 0, stream>>>((const short*)dt16, 64, (const short*)w_dt, 64,
      64, 2048, 2048, 0, dt_b, nullptr, delta_f, nullptr);
  // 7) chunked scan -> y (bf16), fused +xc*D and *silu(z)
  scan_p1<<<dim3(128,16,2), 256, 0, stream>>>(delta_f, xc_f, xdbl_f, A_log, carP, carS);
  scan_p2<<<dim3(256), 256, 0, stream>>>(carP, carS, hin);
  scan_p3<<<dim3(128,16,2), 256, 0, stream>>>(delta_f, xc_f, xdbl_f, xz_b, A_log, Dp, hin, y_b);
  // 8) x2 = x + y @ out_w^T  [2048 x 1024]
  gemm_k<0><<<dim3(16,8), 256, 0, stream>>>((const short*)y_b, 2048, (const short*)w_out, 2048,
      2048, 1024, 1024, 0, nullptr, x, x2_f, nullptr);
  // 9) normed = LN(x2)  (reuse x1_b)
  ln_kernel<<<NROWS, 256, 0, stream>>>(x2_f, n2_g, n2_b, x1_b);
  // 10) gv = normed @ ffg_w^T + ffg_b  [2048 x 2048]  (reuse delta_f)
  gemm_k<0><<<dim3(16,16), 256, 0, stream>>>((const short*)x1_b, 1024, (const short*)w_ffg, 1024,
      1024, 2048, 2048, 0, ffg_b, nullptr, delta_f, nullptr);
  // 11) g = silu(gate)*val -> bf16 (reuse y_b)
  gated_kernel<<<GRID1((long)NROWS*DM), 256, 0, stream>>>(delta_f, y_b);
  // 12) out = x2 + g @ ffp_w^T + ffp_b
  gemm_k<0><<<dim3(16,8), 256, 0, stream>>>((const short*)y_b, 1024, (const short*)w_ffp, 1024,
      1024, 1024, 1024, 0, ffp_b, x2_f, outp, nullptr);
  #undef GRID1
}

// Round 6
// 432.676 us; speedup vs baseline: 1.9798x; 1.1224x over previous
//
#include <hip/hip_runtime.h>
#include <hip/hip_bf16.h>

#define DM 1024
#define DI 2048
#define LSEQ 1024
#define BSZ 2
#define NROWS (BSZ*LSEQ)   // 2048
#define NC 32              // scan chunks
#define CL 32              // chunk length (NC*CL = LSEQ)

typedef __attribute__((ext_vector_type(4))) float f32x4;
typedef __attribute__((ext_vector_type(8))) short bf16x8;
typedef __hip_bfloat16 bf16;

__device__ __forceinline__ float sigmoidf_(float x){ return 1.f/(1.f+__expf(-x)); }

// ---------------- f32 -> bf16 convert (optional row-pad / row-stride) ----------------
__global__ void cvt_kernel(const float* __restrict__ src, bf16* __restrict__ dst,
                           long n, int cols, int src_stride, int src_rows)
{
  long i = (long)blockIdx.x*blockDim.x + threadIdx.x;
  if (i >= n) return;
  int r = (int)(i / cols);
  int c = (int)(i - (long)r*cols);
  float v = (r < src_rows) ? src[(long)r*src_stride + c] : 0.f;
  dst[i] = __float2bfloat16(v);
}

// ---------------- LayerNorm (row=1024) f32 -> bf16 ----------------
__global__ __launch_bounds__(256) void ln_kernel(const float* __restrict__ x,
    const float* __restrict__ g, const float* __restrict__ b, bf16* __restrict__ out)
{
  int row = blockIdx.x;
  float4 v = ((const float4*)(x + (long)row*DM))[threadIdx.x];
  float s  = v.x+v.y+v.z+v.w;
  float s2 = v.x*v.x+v.y*v.y+v.z*v.z+v.w*v.w;
  #pragma unroll
  for (int m=32;m;m>>=1){ s += __shfl_xor(s,m); s2 += __shfl_xor(s2,m); }
  __shared__ float ws0[4], ws1[4];
  int wv = threadIdx.x>>6;
  if ((threadIdx.x&63)==0){ ws0[wv]=s; ws1[wv]=s2; }
  __syncthreads();
  s  = ws0[0]+ws0[1]+ws0[2]+ws0[3];
  s2 = ws1[0]+ws1[1]+ws1[2]+ws1[3];
  float mu  = s*(1.f/DM);
  float var = s2*(1.f/DM) - mu*mu;
  float rs  = rsqrtf(var + 1e-5f);
  int c = threadIdx.x*4;
  float4 gg = ((const float4*)g)[threadIdx.x];
  float4 bb = ((const float4*)b)[threadIdx.x];
  bf16* o = out + (long)row*DM + c;
  o[0] = __float2bfloat16((v.x-mu)*rs*gg.x + bb.x);
  o[1] = __float2bfloat16((v.y-mu)*rs*gg.y + bb.y);
  o[2] = __float2bfloat16((v.z-mu)*rs*gg.z + bb.z);
  o[3] = __float2bfloat16((v.w-mu)*rs*gg.w + bb.w);
}

// ---------------- bf16 MFMA GEMM: C[M,N] = A[M,K] @ B[N,K]^T (+bias)(+act)(+res) ----
// 128x128 tile, 256 threads (4 waves), each wave 64x64 via 4x4 frags of 16x16x32.
// ACT: 0=none, 1=softplus (fast: v_exp + v_log)
template<int ACT>
__global__ __launch_bounds__(256)
void gemm_k(const short* __restrict__ A, int lda, const short* __restrict__ B, int ldb,
            int K, int Nreal, int ldo, int pstride,
            const float* __restrict__ bias, const float* __restrict__ res,
            float* __restrict__ outf, bf16* __restrict__ outb)
{
  A += (size_t)blockIdx.z * K;
  B += (size_t)blockIdx.z * K;
  if (outf) outf += (size_t)blockIdx.z * pstride;

  __shared__ short As[128*32];
  __shared__ short Bs[128*32];
  const int tid  = threadIdx.x;
  const int wave = tid>>6, lane = tid&63;
  const int m0 = blockIdx.x*128, n0 = blockIdx.y*128;
  const int wm = (wave>>1)*64, wn = (wave&1)*64;
  const int lr = lane&15, lk = lane>>4;

  f32x4 acc[4][4];
  #pragma unroll
  for (int i=0;i<4;i++)
    #pragma unroll
    for (int j=0;j<4;j++) acc[i][j] = f32x4{0.f,0.f,0.f,0.f};

  const int r0 = tid>>2;        // 0..63
  const int kb = (tid&3)*8;     // 0,8,16,24 (bf16 elems)

  for (int kt=0; kt<K; kt+=32) {
    #pragma unroll
    for (int i=0;i<2;i++){
      int row = r0 + i*64;
      __builtin_amdgcn_global_load_lds(
        (const __attribute__((address_space(1))) void*)(A + (size_t)(m0+row)*lda + kt + kb),
        (__attribute__((address_space(3))) void*)(As + row*32 + kb), 16, 0, 0);
    }
    #pragma unroll
    for (int i=0;i<2;i++){
      int row = r0 + i*64;
      __builtin_amdgcn_global_load_lds(
        (const __attribute__((address_space(1))) void*)(B + (size_t)(n0+row)*ldb + kt + kb),
        (__attribute__((address_space(3))) void*)(Bs + row*32 + kb), 16, 0, 0);
    }
    asm volatile("s_waitcnt vmcnt(0)");
    __syncthreads();
    bf16x8 af[4], bfr[4];
    #pragma unroll
    for (int i=0;i<4;i++) af[i]  = *(const bf16x8*)(As + (wm+i*16+lr)*32 + lk*8);
    #pragma unroll
    for (int j=0;j<4;j++) bfr[j] = *(const bf16x8*)(Bs + (wn+j*16+lr)*32 + lk*8);
    #pragma unroll
    for (int i=0;i<4;i++)
      #pragma unroll
      for (int j=0;j<4;j++)
        acc[i][j] = __builtin_amdgcn_mfma_f32_16x16x32_bf16(af[i], bfr[j], acc[i][j], 0,0,0);
    __syncthreads();
  }

  // epilogue: C/D map col=lane&15, row=(lane>>4)*4+reg   [m89-verified]
  #pragma unroll
  for (int i=0;i<4;i++){
    #pragma unroll
    for (int j=0;j<4;j++){
      int col = n0 + wn + j*16 + lr;
      if (col >= Nreal) continue;
      #pragma unroll
      for (int r=0;r<4;r++){
        int row = m0 + wm + i*16 + lk*4 + r;
        float v = acc[i][j][r];
        if (bias) v += bias[col];
        if (ACT==1){
          float ev = __expf(v);
          v = (v > 20.f) ? v : __logf(1.f + ev);
        }
        if (res)  v += res[(size_t)row*ldo + col];
        if (outf) outf[(size_t)row*ldo + col] = v;
        if (outb) outb[(size_t)row*ldo + col] = __float2bfloat16(v);
      }
    }
  }
}

// ---------------- split-K reduce for x_proj; fuses dt bf16 slice --------------------
__global__ __launch_bounds__(256) void xproj_reduce(const float* __restrict__ part,
    float* __restrict__ xdbl, bf16* __restrict__ dt16)
{
  int i = blockIdx.x*256 + threadIdx.x;
  if (i >= NROWS*96) return;
  float s = 0.f;
  #pragma unroll
  for (int k=0;k<8;k++) s += part[(long)k*(NROWS*96) + i];
  xdbl[i] = s;
  int r = i/96, c = i - r*96;
  if (c < 64) dt16[r*64 + c] = __float2bfloat16(s);
}

// ---------------- depthwise causal conv(4) + silu; writes f32 + bf16 ----------------
__global__ __launch_bounds__(256) void conv_kernel(const bf16* __restrict__ xz,
    const float* __restrict__ w, const float* __restrict__ cb,
    float* __restrict__ xcf, bf16* __restrict__ xcb)
{
  long i = (long)blockIdx.x*blockDim.x + threadIdx.x;  // NROWS*DI
  int d  = (int)(i & (DI-1));
  int bl = (int)(i >> 11);
  int l  = bl & (LSEQ-1);
  int b  = bl >> 10;
  float acc = cb[d];
  #pragma unroll
  for (int k=0;k<4;k++){
    int ls = l-3+k;
    if (ls >= 0)
      acc += __bfloat162float(xz[(long)(b*LSEQ+ls)*(2*DI) + d]) * w[d*4+k];
  }
  float s = acc * sigmoidf_(acc);
  xcf[i] = s;
  xcb[i] = __float2bfloat16(s);
}

// ======================= chunked SSM scan, states-in-registers ======================
// thread = one (b, d, chunk); 16 n-states live in VGPRs. No cross-lane ops.
// a_n = exp(du*Aneg_n); h_n = a_n*h_n + du*xv*B_n; y = sum_n h_n*C_n + xv*D.
// Chunk carry: S_n (scan from 0) + sumDu (P_n = exp(Aneg_n*sumDu), exact identity).

#define H16(du, duxv, B0,B1,B2,B3) \
  h0  = __expf((du)*An0 )*h0  + (duxv)*(B0).x; \
  h1  = __expf((du)*An1 )*h1  + (duxv)*(B0).y; \
  h2  = __expf((du)*An2 )*h2  + (duxv)*(B0).z; \
  h3  = __expf((du)*An3 )*h3  + (duxv)*(B0).w; \
  h4  = __expf((du)*An4 )*h4  + (duxv)*(B1).x; \
  h5  = __expf((du)*An5 )*h5  + (duxv)*(B1).y; \
  h6  = __expf((du)*An6 )*h6  + (duxv)*(B1).z; \
  h7  = __expf((du)*An7 )*h7  + (duxv)*(B1).w; \
  h8  = __expf((du)*An8 )*h8  + (duxv)*(B2).x; \
  h9  = __expf((du)*An9 )*h9  + (duxv)*(B2).y; \
  h10 = __expf((du)*An10)*h10 + (duxv)*(B2).z; \
  h11 = __expf((du)*An11)*h11 + (duxv)*(B2).w; \
  h12 = __expf((du)*An12)*h12 + (duxv)*(B3).x; \
  h13 = __expf((du)*An13)*h13 + (duxv)*(B3).y; \
  h14 = __expf((du)*An14)*h14 + (duxv)*(B3).z; \
  h15 = __expf((du)*An15)*h15 + (duxv)*(B3).w;

#define DECL_AN(Alog_ptr, d) \
  float4 al0 = ((const float4*)((Alog_ptr) + (d)*16))[0]; \
  float4 al1 = ((const float4*)((Alog_ptr) + (d)*16))[1]; \
  float4 al2 = ((const float4*)((Alog_ptr) + (d)*16))[2]; \
  float4 al3 = ((const float4*)((Alog_ptr) + (d)*16))[3]; \
  float An0=-__expf(al0.x), An1=-__expf(al0.y), An2 =-__expf(al0.z), An3 =-__expf(al0.w); \
  float An4=-__expf(al1.x), An5=-__expf(al1.y), An6 =-__expf(al1.z), An7 =-__expf(al1.w); \
  float An8=-__expf(al2.x), An9=-__expf(al2.y), An10=-__expf(al2.z), An11=-__expf(al2.w); \
  float An12=-__expf(al3.x),An13=-__expf(al3.y),An14=-__expf(al3.z), An15=-__expf(al3.w);

// phase1: per-chunk S (scan from 0) + sumDu
__global__ __launch_bounds__(256) void scan_p1(
    const float* __restrict__ delta, const float* __restrict__ xc,
    const float* __restrict__ xdbl, const float* __restrict__ A_log,
    float* __restrict__ S, float* __restrict__ sumDu)
{
  const int tid = threadIdx.x;
  const int d   = blockIdx.x*256 + tid;
  const int c   = blockIdx.y, b = blockIdx.z;
  const int bd  = b*2048 + d;
  DECL_AN(A_log, d);
  __shared__ float sB[CL][16];
  {
    int e = tid*2;                       // 512 = CL*16 elems, 2 per thread
    int r = e>>4, n = e&15;
    long row = (long)b*LSEQ + c*CL + r;
    sB[r][n]   = xdbl[row*96 + 64 + n];
    sB[r][n+1] = xdbl[row*96 + 64 + n+1];
  }
  __syncthreads();
  float h0=0,h1=0,h2=0,h3=0,h4=0,h5=0,h6=0,h7=0,
        h8=0,h9=0,h10=0,h11=0,h12=0,h13=0,h14=0,h15=0;
  float sdu = 0.f;
  const long rbase = (long)b*LSEQ + c*CL;
  #pragma unroll
  for (int s0=0; s0<CL; s0+=8){
    float du8[8], xv8[8];
    #pragma unroll
    for (int i=0;i<8;i++){
      long row = rbase + s0 + i;
      du8[i] = delta[row*DI + d];
      xv8[i] = xc[row*DI + d];
    }
    #pragma unroll
    for (int i=0;i<8;i++){
      float du = du8[i], duxv = du*xv8[i];
      sdu += du;
      const float4* bb = (const float4*)sB[s0+i];
      float4 B0=bb[0], B1=bb[1], B2=bb[2], B3=bb[3];
      H16(du, duxv, B0,B1,B2,B3);
    }
  }
  sumDu[c*4096 + bd] = sdu;
  float hs[16] = {h0,h1,h2,h3,h4,h5,h6,h7,h8,h9,h10,h11,h12,h13,h14,h15};
  #pragma unroll
  for (int n=0;n<16;n++) S[(c*16+n)*4096 + bd] = hs[n];
}

// phase2: compose carries serially over chunks -> per-chunk initial state
__global__ __launch_bounds__(256) void scan_p2(const float* __restrict__ S,
    const float* __restrict__ sumDu, const float* __restrict__ A_log,
    float* __restrict__ hin)
{
  int t = blockIdx.x*256 + threadIdx.x;    // 65536 = 16n * 4096bd
  int n = t >> 12, bd = t & 4095;
  int d = bd & 2047;
  float Aneg = -__expf(A_log[d*16 + n]);
  float h = 0.f;
  #pragma unroll
  for (int c=0;c<NC;c++){
    hin[(c*16+n)*4096 + bd] = h;
    float P = __expf(Aneg * sumDu[c*4096 + bd]);
    h = S[(c*16+n)*4096 + bd] + P*h;
  }
}

// phase3: within-chunk scan from hin; fused y = (sum_n h*C + xc*D)*silu(z) -> bf16
__global__ __launch_bounds__(256) void scan_p3(
    const float* __restrict__ delta, const float* __restrict__ xc,
    const float* __restrict__ xdbl, const bf16* __restrict__ xz,
    const float* __restrict__ A_log, const float* __restrict__ Dp,
    const float* __restrict__ hin, bf16* __restrict__ y)
{
  const int tid = threadIdx.x;
  const int d   = blockIdx.x*256 + tid;
  const int c   = blockIdx.y, b = blockIdx.z;
  const int bd  = b*2048 + d;
  DECL_AN(A_log, d);
  const float Dd = Dp[d];
  __shared__ float sB[CL][16], sC[CL][16];
  {
    int e = tid*2;
    int r = e>>4, n = e&15;
    long row = (long)b*LSEQ + c*CL + r;
    sB[r][n]   = xdbl[row*96 + 64 + n];
    sB[r][n+1] = xdbl[row*96 + 64 + n+1];
    sC[r][n]   = xdbl[row*96 + 80 + n];
    sC[r][n+1] = xdbl[row*96 + 80 + n+1];
  }
  __syncthreads();
  float h0,h1,h2,h3,h4,h5,h6,h7,h8,h9,h10,h11,h12,h13,h14,h15;
  {
    const float* hp = hin + c*16*4096 + bd;
    h0 =hp[0];       h1 =hp[4096];    h2 =hp[2*4096];  h3 =hp[3*4096];
    h4 =hp[4*4096];  h5 =hp[5*4096];  h6 =hp[6*4096];  h7 =hp[7*4096];
    h8 =hp[8*4096];  h9 =hp[9*4096];  h10=hp[10*4096]; h11=hp[11*4096];
    h12=hp[12*4096]; h13=hp[13*4096]; h14=hp[14*4096]; h15=hp[15*4096];
  }
  const long rbase = (long)b*LSEQ + c*CL;
  #pragma unroll
  for (int s0=0; s0<CL; s0+=8){
    float du8[8], xv8[8], zv8[8];
    #pragma unroll
    for (int i=0;i<8;i++){
      long row = rbase + s0 + i;
      du8[i] = delta[row*DI + d];
      xv8[i] = xc[row*DI + d];
      zv8[i] = __bfloat162float(xz[row*(2*DI) + DI + d]);
    }
    #pragma unroll
    for (int i=0;i<8;i++){
      float du = du8[i], xv = xv8[i], duxv = du*xv;
      const float4* bb = (const float4*)sB[s0+i];
      float4 B0=bb[0], B1=bb[1], B2=bb[2], B3=bb[3];
      H16(du, duxv, B0,B1,B2,B3);
      const float4* cc = (const float4*)sC[s0+i];
      float4 C0=cc[0], C1=cc[1], C2=cc[2], C3=cc[3];
      float r0 = h0*C0.x + h4*C1.x + h8 *C2.x + h12*C3.x;
      float r1 = h1*C0.y + h5*C1.y + h9 *C2.y + h13*C3.y;
      float r2 = h2*C0.z + h6*C1.z + h10*C2.z + h14*C3.z;
      float r3 = h3*C0.w + h7*C1.w + h11*C2.w + h15*C3.w;
      float r = (r0+r1) + (r2+r3) + xv*Dd;
      float z = zv8[i];
      y[(rbase+s0+i)*DI + d] = __float2bfloat16(r * (z*sigmoidf_(z)));
    }
  }
}

// ---------------- gated: g = silu(gv[:, :1024]) * gv[:, 1024:] -> bf16 -------------
__global__ __launch_bounds__(256) void gated_kernel(const float* __restrict__ gv,
                                                    bf16* __restrict__ g)
{
  long i = (long)blockIdx.x*blockDim.x + threadIdx.x;  // NROWS*DM
  int r = (int)(i >> 10);
  int c = (int)(i & (DM-1));
  float gt = gv[(long)r*(2*DM) + c];
  float vl = gv[(long)r*(2*DM) + DM + c];
  g[i] = __float2bfloat16(gt * sigmoidf_(gt) * vl);
}

// ------------------------------- launcher ------------------------------------------
extern "C" void kernel_launch(void* const* d_in, const int* in_sizes, int n_in,
                              void* d_out, int out_size, void* d_ws, size_t ws_size,
                              hipStream_t stream)
{
  const float* x        = (const float*)d_in[0];
  const float* n1_g     = (const float*)d_in[1];
  const float* n1_b     = (const float*)d_in[2];
  const float* n2_g     = (const float*)d_in[3];
  const float* n2_b     = (const float*)d_in[4];
  const float* in_proj_w= (const float*)d_in[5];
  const float* conv_w   = (const float*)d_in[6];
  const float* conv_b   = (const float*)d_in[7];
  const float* x_proj_w = (const float*)d_in[8];
  const float* dt_w     = (const float*)d_in[9];
  const float* dt_b     = (const float*)d_in[10];
  const float* A_log    = (const float*)d_in[11];
  const float* Dp       = (const float*)d_in[12];
  const float* out_w    = (const float*)d_in[13];
  const float* ffg_w    = (const float*)d_in[14];
  const float* ffg_b    = (const float*)d_in[15];
  const float* ffp_w    = (const float*)d_in[16];
  const float* ffp_b    = (const float*)d_in[17];

  char* ws = (char*)d_ws;
  // bf16 buffers
  bf16* w_inproj = (bf16*)(ws + 0);          // 4096x1024
  bf16* w_xproj  = (bf16*)(ws + 8388608);    // 128x2048 (zero-pad from 96 rows)
  bf16* w_dt     = (bf16*)(ws + 8912896);    // 2048x64
  bf16* w_out    = (bf16*)(ws + 9175040);    // 1024x2048
  bf16* w_ffg    = (bf16*)(ws + 13369344);   // 2048x1024
  bf16* w_ffp    = (bf16*)(ws + 17563648);   // 1024x1024
  bf16* x1_b     = (bf16*)(ws + 19660800);   // 2048x1024 (reused: normed)
  bf16* xz_b     = (bf16*)(ws + 23855104);   // 2048x4096
  bf16* xc_b     = (bf16*)(ws + 40632320);   // 2048x2048 (dead after x_proj)
  float* S_buf   = (float*)(ws + 40632320);  //   reused: scan S [32c][16n][4096bd] = 8 MB
  float* sumDu   = (float*)(ws + 8388608);   //   reused (w_xproj dead): [32c][4096bd] = 512 KB
  bf16* dt16     = (bf16*)(ws + 49020928);   // 2048x64
  bf16* y_b      = (bf16*)(ws + 49283072);   // 2048x2048 (reused: g 2048x1024)
  // f32 buffers
  float* xc_f    = (float*)(ws + 57671680);  // 2048x2048
  float* xdbl_f  = (float*)(ws + 74448896);  // 2048x96
  float* delta_f = (float*)(ws + 75235328);  // 2048x2048 (pre-used: x_proj partials; reused: gv)
  float* part_xp = (float*)(ws + 75235328);  // 8x2048x96 partials (dead before delta write)
  float* x2_f    = (float*)(ws + 92012544);  // 2048x1024 (first 8MB pre-used as hin)
  float* hin     = (float*)(ws + 92012544);  // [32c][16n][4096bd] = 8 MB (dead before x2 write)
  float* outp    = (float*)d_out;            // 2048x1024

  #define GRID1(n) dim3((int)(((n)+255)/256))
  // weight converts
  cvt_kernel<<<GRID1(4096L*1024), 256, 0, stream>>>(in_proj_w, w_inproj, 4096L*1024, 1024, 1024, 4096);
  cvt_kernel<<<GRID1(128L*2048), 256, 0, stream>>>(x_proj_w,  w_xproj,  128L*2048, 2048, 2048, 96);
  cvt_kernel<<<GRID1(2048L*64),  256, 0, stream>>>(dt_w,      w_dt,     2048L*64,   64,   64, 2048);
  cvt_kernel<<<GRID1(1024L*2048),256, 0, stream>>>(out_w,     w_out,    1024L*2048, 2048, 2048, 1024);
  cvt_kernel<<<GRID1(2048L*1024),256, 0, stream>>>(ffg_w,     w_ffg,    2048L*1024, 1024, 1024, 2048);
  cvt_kernel<<<GRID1(1024L*1024),256, 0, stream>>>(ffp_w,     w_ffp,    1024L*1024, 1024, 1024, 1024);

  // 1) x1 = LN(x)
  ln_kernel<<<NROWS, 256, 0, stream>>>(x, n1_g, n1_b, x1_b);
  // 2) xz = x1 @ in_proj_w^T   [2048 x 4096]
  gemm_k<0><<<dim3(16,32), 256, 0, stream>>>((const short*)x1_b, 1024, (const short*)w_inproj, 1024,
      1024, 4096, 4096, 0, nullptr, nullptr, nullptr, xz_b);
  // 3) xc = silu(causal_conv(x_in)+cb)
  conv_kernel<<<GRID1((long)NROWS*DI), 256, 0, stream>>>(xz_b, conv_w, conv_b, xc_f, xc_b);
  // 4) x_dbl partials = xc @ x_proj_w^T  [2048 x 96], split-K 8x256
  gemm_k<0><<<dim3(16,1,8), 256, 0, stream>>>((const short*)xc_b, 2048, (const short*)w_xproj, 2048,
      256, 96, 96, NROWS*96, nullptr, nullptr, part_xp, nullptr);
  // 5) reduce partials -> xdbl_f (+ dt16 bf16 slice)
  xproj_reduce<<<GRID1((long)NROWS*96), 256, 0, stream>>>(part_xp, xdbl_f, dt16);
  // 6) delta = softplus(dt @ dt_w^T + dt_b)  [2048 x 2048]
  gemm_k<1><<<dim3(16,16), 256, 0, stream>>>((const short*)dt16, 64, (const short*)w_dt, 64,
      64, 2048, 2048, 0, dt_b, nullptr, delta_f, nullptr);
  // 7) chunked scan (states-in-registers) -> y (bf16), fused +xc*D and *silu(z)
  scan_p1<<<dim3(8,NC,2), 256, 0, stream>>>(delta_f, xc_f, xdbl_f, A_log, S_buf, sumDu);
  scan_p2<<<dim3(256), 256, 0, stream>>>(S_buf, sumDu, A_log, hin);
  scan_p3<<<dim3(8,NC,2), 256, 0, stream>>>(delta_f, xc_f, xdbl_f, xz_b, A_log, Dp, hin, y_b);
  // 8) x2 = x + y @ out_w^T  [2048 x 1024]
  gemm_k<0><<<dim3(16,8), 256, 0, stream>>>((const short*)y_b, 2048, (const short*)w_out, 2048,
      2048, 1024, 1024, 0, nullptr, x, x2_f, nullptr);
  // 9) normed = LN(x2)  (reuse x1_b)
  ln_kernel<<<NROWS, 256, 0, stream>>>(x2_f, n2_g, n2_b, x1_b);
  // 10) gv = normed @ ffg_w^T + ffg_b  [2048 x 2048]  (reuse delta_f)
  gemm_k<0><<<dim3(16,16), 256, 0, stream>>>((const short*)x1_b, 1024, (const short*)w_ffg, 1024,
      1024, 2048, 2048, 0, ffg_b, nullptr, delta_f, nullptr);
  // 11) g = silu(gate)*val -> bf16 (reuse y_b)
  gated_kernel<<<GRID1((long)NROWS*DM), 256, 0, stream>>>(delta_f, y_b);
  // 12) out = x2 + g @ ffp_w^T + ffp_b
  gemm_k<0><<<dim3(16,8), 256, 0, stream>>>((const short*)y_b, 1024, (const short*)w_ffp, 1024,
      1024, 1024, 1024, 0, ffp_b, x2_f, outp, nullptr);
  #undef GRID1
}

// Round 7
// 375.010 us; speedup vs baseline: 2.2842x; 1.1538x over previous
//
#include <hip/hip_runtime.h>
#include <hip/hip_bf16.h>

#define DM 1024
#define DI 2048
#define LSEQ 1024
#define BSZ 2
#define NROWS (BSZ*LSEQ)   // 2048
#define NC 32              // scan chunks
#define CL 32              // chunk length (NC*CL = LSEQ)

typedef __attribute__((ext_vector_type(4))) float f32x4;
typedef __attribute__((ext_vector_type(8))) short bf16x8;
typedef __hip_bfloat16 bf16;

__device__ __forceinline__ float sigmoidf_(float x){ return 1.f/(1.f+__expf(-x)); }

// ---------------- f32 -> bf16 convert (optional row-pad / row-stride) ----------------
__global__ void cvt_kernel(const float* __restrict__ src, bf16* __restrict__ dst,
                           long n, int cols, int src_stride, int src_rows)
{
  long i = (long)blockIdx.x*blockDim.x + threadIdx.x;
  if (i >= n) return;
  int r = (int)(i / cols);
  int c = (int)(i - (long)r*cols);
  float v = (r < src_rows) ? src[(long)r*src_stride + c] : 0.f;
  dst[i] = __float2bfloat16(v);
}

// ---------------- LayerNorm (row=1024) f32 -> bf16 ----------------
__global__ __launch_bounds__(256) void ln_kernel(const float* __restrict__ x,
    const float* __restrict__ g, const float* __restrict__ b, bf16* __restrict__ out)
{
  int row = blockIdx.x;
  float4 v = ((const float4*)(x + (long)row*DM))[threadIdx.x];
  float s  = v.x+v.y+v.z+v.w;
  float s2 = v.x*v.x+v.y*v.y+v.z*v.z+v.w*v.w;
  #pragma unroll
  for (int m=32;m;m>>=1){ s += __shfl_xor(s,m); s2 += __shfl_xor(s2,m); }
  __shared__ float ws0[4], ws1[4];
  int wv = threadIdx.x>>6;
  if ((threadIdx.x&63)==0){ ws0[wv]=s; ws1[wv]=s2; }
  __syncthreads();
  s  = ws0[0]+ws0[1]+ws0[2]+ws0[3];
  s2 = ws1[0]+ws1[1]+ws1[2]+ws1[3];
  float mu  = s*(1.f/DM);
  float var = s2*(1.f/DM) - mu*mu;
  float rs  = rsqrtf(var + 1e-5f);
  int c = threadIdx.x*4;
  float4 gg = ((const float4*)g)[threadIdx.x];
  float4 bb = ((const float4*)b)[threadIdx.x];
  bf16* o = out + (long)row*DM + c;
  o[0] = __float2bfloat16((v.x-mu)*rs*gg.x + bb.x);
  o[1] = __float2bfloat16((v.y-mu)*rs*gg.y + bb.y);
  o[2] = __float2bfloat16((v.z-mu)*rs*gg.z + bb.z);
  o[3] = __float2bfloat16((v.w-mu)*rs*gg.w + bb.w);
}

// ---------------- bf16 MFMA GEMM: C[M,N] = A[M,K] @ B[N,K]^T (+bias)(+act)(+res) ----
// 128x128 tile, 256 threads (4 waves), each wave 64x64 via 4x4 frags of 16x16x32.
// Double-buffered LDS prefetch (T3 minimum): STAGE(t+1) issued BEFORE compute(t);
// one vmcnt(0)+barrier per K-step. ACT: 0=none, 1=softplus (fast v_exp+v_log).
// blockIdx.z = K-split index (A,B advance z*K; outf by z*pstride).
template<int ACT>
__global__ __launch_bounds__(256)
void gemm_k(const short* __restrict__ A, int lda, const short* __restrict__ B, int ldb,
            int K, int Nreal, int ldo, int pstride,
            const float* __restrict__ bias, const float* __restrict__ res,
            float* __restrict__ outf, bf16* __restrict__ outb)
{
  A += (size_t)blockIdx.z * K;
  B += (size_t)blockIdx.z * K;
  if (outf) outf += (size_t)blockIdx.z * pstride;

  __shared__ short As[2][128*32];
  __shared__ short Bs[2][128*32];
  const int tid  = threadIdx.x;
  const int wave = tid>>6, lane = tid&63;
  const int m0 = blockIdx.x*128, n0 = blockIdx.y*128;
  const int wm = (wave>>1)*64, wn = (wave&1)*64;
  const int lr = lane&15, lk = lane>>4;

  f32x4 acc[4][4];
  #pragma unroll
  for (int i=0;i<4;i++)
    #pragma unroll
    for (int j=0;j<4;j++) acc[i][j] = f32x4{0.f,0.f,0.f,0.f};

  const int r0 = tid>>2;        // 0..63
  const int kb = (tid&3)*8;     // 0,8,16,24 (bf16 elems)
  const short* Arow = A + (size_t)(m0+r0)*lda + kb;
  const short* Brow = B + (size_t)(n0+r0)*ldb + kb;

#define STAGE_T(buf, kt) do { \
    __builtin_amdgcn_global_load_lds((const __attribute__((address_space(1))) void*)(Arow + (kt)), \
        (__attribute__((address_space(3))) void*)(&As[buf][r0*32+kb]), 16, 0, 0); \
    __builtin_amdgcn_global_load_lds((const __attribute__((address_space(1))) void*)(Arow + (size_t)64*lda + (kt)), \
        (__attribute__((address_space(3))) void*)(&As[buf][(r0+64)*32+kb]), 16, 0, 0); \
    __builtin_amdgcn_global_load_lds((const __attribute__((address_space(1))) void*)(Brow + (kt)), \
        (__attribute__((address_space(3))) void*)(&Bs[buf][r0*32+kb]), 16, 0, 0); \
    __builtin_amdgcn_global_load_lds((const __attribute__((address_space(1))) void*)(Brow + (size_t)64*ldb + (kt)), \
        (__attribute__((address_space(3))) void*)(&Bs[buf][(r0+64)*32+kb]), 16, 0, 0); \
  } while(0)

  STAGE_T(0, 0);
  asm volatile("s_waitcnt vmcnt(0)");
  __syncthreads();
  int cur = 0;
  for (int kt = 32; kt <= K; kt += 32) {
    if (kt < K) STAGE_T(cur^1, kt);   // prefetch next tile while computing current
    bf16x8 af[4], bfr[4];
    #pragma unroll
    for (int i=0;i<4;i++) af[i]  = *(const bf16x8*)(&As[cur][(wm+i*16+lr)*32 + lk*8]);
    #pragma unroll
    for (int j=0;j<4;j++) bfr[j] = *(const bf16x8*)(&Bs[cur][(wn+j*16+lr)*32 + lk*8]);
    #pragma unroll
    for (int i=0;i<4;i++)
      #pragma unroll
      for (int j=0;j<4;j++)
        acc[i][j] = __builtin_amdgcn_mfma_f32_16x16x32_bf16(af[i], bfr[j], acc[i][j], 0,0,0);
    asm volatile("s_waitcnt vmcnt(0)");
    __syncthreads();
    cur ^= 1;
  }
#undef STAGE_T

  // epilogue: C/D map col=lane&15, row=(lane>>4)*4+reg   [m89-verified]
  #pragma unroll
  for (int i=0;i<4;i++){
    #pragma unroll
    for (int j=0;j<4;j++){
      int col = n0 + wn + j*16 + lr;
      if (col >= Nreal) continue;
      #pragma unroll
      for (int r=0;r<4;r++){
        int row = m0 + wm + i*16 + lk*4 + r;
        float v = acc[i][j][r];
        if (bias) v += bias[col];
        if (ACT==1){
          float ev = __expf(v);
          v = (v > 20.f) ? v : __logf(1.f + ev);
        }
        if (res)  v += res[(size_t)row*ldo + col];
        if (outf) outf[(size_t)row*ldo + col] = v;
        if (outb) outb[(size_t)row*ldo + col] = __float2bfloat16(v);
      }
    }
  }
}

// ---------------- split-K=2 reduce: out = p0+p1 (+bias) (+res) -> f32 ---------------
__global__ __launch_bounds__(256) void red2_kernel(
    const float* __restrict__ p0, const float* __restrict__ p1,
    const float* __restrict__ bias, const float* __restrict__ res,
    float* __restrict__ outf)
{
  long i = ((long)blockIdx.x*256 + threadIdx.x)*4;   // over 2048x1024 f32
  float4 a = *(const float4*)(p0+i);
  float4 b = *(const float4*)(p1+i);
  float4 o = {a.x+b.x, a.y+b.y, a.z+b.z, a.w+b.w};
  if (bias){
    const float4 bb = *(const float4*)(bias + (int)(i & (DM-1)));
    o.x+=bb.x; o.y+=bb.y; o.z+=bb.z; o.w+=bb.w;
  }
  if (res){
    float4 r = *(const float4*)(res+i);
    o.x+=r.x; o.y+=r.y; o.z+=r.z; o.w+=r.w;
  }
  *(float4*)(outf+i) = o;
}

// ---------------- split-K reduce for x_proj; fuses dt bf16 slice --------------------
__global__ __launch_bounds__(256) void xproj_reduce(const float* __restrict__ part,
    float* __restrict__ xdbl, bf16* __restrict__ dt16)
{
  int i = blockIdx.x*256 + threadIdx.x;
  if (i >= NROWS*96) return;
  float s = 0.f;
  #pragma unroll
  for (int k=0;k<8;k++) s += part[(long)k*(NROWS*96) + i];
  xdbl[i] = s;
  int r = i/96, c = i - r*96;
  if (c < 64) dt16[r*64 + c] = __float2bfloat16(s);
}

// ---------------- depthwise causal conv(4) + silu; writes f32 + bf16 ----------------
__global__ __launch_bounds__(256) void conv_kernel(const bf16* __restrict__ xz,
    const float* __restrict__ w, const float* __restrict__ cb,
    float* __restrict__ xcf, bf16* __restrict__ xcb)
{
  long i = (long)blockIdx.x*blockDim.x + threadIdx.x;  // NROWS*DI
  int d  = (int)(i & (DI-1));
  int bl = (int)(i >> 11);
  int l  = bl & (LSEQ-1);
  int b  = bl >> 10;
  float acc = cb[d];
  #pragma unroll
  for (int k=0;k<4;k++){
    int ls = l-3+k;
    if (ls >= 0)
      acc += __bfloat162float(xz[(long)(b*LSEQ+ls)*(2*DI) + d]) * w[d*4+k];
  }
  float s = acc * sigmoidf_(acc);
  xcf[i] = s;
  xcb[i] = __float2bfloat16(s);
}

// ======================= chunked SSM scan, states-in-registers ======================
// thread = one (b, d, chunk); 16 n-states live in VGPRs. No cross-lane ops.
// a_n = exp(du*Aneg_n); h_n = a_n*h_n + du*xv*B_n; y = sum_n h_n*C_n + xv*D.
// Chunk carry: S_n (scan from 0) + sumDu (P_n = exp(Aneg_n*sumDu), exact identity).

#define H16(du, duxv, B0,B1,B2,B3) \
  h0  = __expf((du)*An0 )*h0  + (duxv)*(B0).x; \
  h1  = __expf((du)*An1 )*h1  + (duxv)*(B0).y; \
  h2  = __expf((du)*An2 )*h2  + (duxv)*(B0).z; \
  h3  = __expf((du)*An3 )*h3  + (duxv)*(B0).w; \
  h4  = __expf((du)*An4 )*h4  + (duxv)*(B1).x; \
  h5  = __expf((du)*An5 )*h5  + (duxv)*(B1).y; \
  h6  = __expf((du)*An6 )*h6  + (duxv)*(B1).z; \
  h7  = __expf((du)*An7 )*h7  + (duxv)*(B1).w; \
  h8  = __expf((du)*An8 )*h8  + (duxv)*(B2).x; \
  h9  = __expf((du)*An9 )*h9  + (duxv)*(B2).y; \
  h10 = __expf((du)*An10)*h10 + (duxv)*(B2).z; \
  h11 = __expf((du)*An11)*h11 + (duxv)*(B2).w; \
  h12 = __expf((du)*An12)*h12 + (duxv)*(B3).x; \
  h13 = __expf((du)*An13)*h13 + (duxv)*(B3).y; \
  h14 = __expf((du)*An14)*h14 + (duxv)*(B3).z; \
  h15 = __expf((du)*An15)*h15 + (duxv)*(B3).w;

#define DECL_AN(Alog_ptr, d) \
  float4 al0 = ((const float4*)((Alog_ptr) + (d)*16))[0]; \
  float4 al1 = ((const float4*)((Alog_ptr) + (d)*16))[1]; \
  float4 al2 = ((const float4*)((Alog_ptr) + (d)*16))[2]; \
  float4 al3 = ((const float4*)((Alog_ptr) + (d)*16))[3]; \
  float An0=-__expf(al0.x), An1=-__expf(al0.y), An2 =-__expf(al0.z), An3 =-__expf(al0.w); \
  float An4=-__expf(al1.x), An5=-__expf(al1.y), An6 =-__expf(al1.z), An7 =-__expf(al1.w); \
  float An8=-__expf(al2.x), An9=-__expf(al2.y), An10=-__expf(al2.z), An11=-__expf(al2.w); \
  float An12=-__expf(al3.x),An13=-__expf(al3.y),An14=-__expf(al3.z), An15=-__expf(al3.w);

// phase1: per-chunk S (scan from 0) + sumDu
__global__ __launch_bounds__(256) void scan_p1(
    const float* __restrict__ delta, const float* __restrict__ xc,
    const float* __restrict__ xdbl, const float* __restrict__ A_log,
    float* __restrict__ S, float* __restrict__ sumDu)
{
  const int tid = threadIdx.x;
  const int d   = blockIdx.x*256 + tid;
  const int c   = blockIdx.y, b = blockIdx.z;
  const int bd  = b*2048 + d;
  DECL_AN(A_log, d);
  __shared__ float sB[CL][16];
  {
    int e = tid*2;                       // 512 = CL*16 elems, 2 per thread
    int r = e>>4, n = e&15;
    long row = (long)b*LSEQ + c*CL + r;
    sB[r][n]   = xdbl[row*96 + 64 + n];
    sB[r][n+1] = xdbl[row*96 + 64 + n+1];
  }
  __syncthreads();
  float h0=0,h1=0,h2=0,h3=0,h4=0,h5=0,h6=0,h7=0,
        h8=0,h9=0,h10=0,h11=0,h12=0,h13=0,h14=0,h15=0;
  float sdu = 0.f;
  const long rbase = (long)b*LSEQ + c*CL;
  #pragma unroll
  for (int s0=0; s0<CL; s0+=8){
    float du8[8], xv8[8];
    #pragma unroll
    for (int i=0;i<8;i++){
      long row = rbase + s0 + i;
      du8[i] = delta[row*DI + d];
      xv8[i] = xc[row*DI + d];
    }
    #pragma unroll
    for (int i=0;i<8;i++){
      float du = du8[i], duxv = du*xv8[i];
      sdu += du;
      const float4* bb = (const float4*)sB[s0+i];
      float4 B0=bb[0], B1=bb[1], B2=bb[2], B3=bb[3];
      H16(du, duxv, B0,B1,B2,B3);
    }
  }
  sumDu[c*4096 + bd] = sdu;
  float hs[16] = {h0,h1,h2,h3,h4,h5,h6,h7,h8,h9,h10,h11,h12,h13,h14,h15};
  #pragma unroll
  for (int n=0;n<16;n++) S[(c*16+n)*4096 + bd] = hs[n];
}

// phase2: compose carries serially over chunks -> per-chunk initial state
__global__ __launch_bounds__(256) void scan_p2(const float* __restrict__ S,
    const float* __restrict__ sumDu, const float* __restrict__ A_log,
    float* __restrict__ hin)
{
  int t = blockIdx.x*256 + threadIdx.x;    // 65536 = 16n * 4096bd
  int n = t >> 12, bd = t & 4095;
  int d = bd & 2047;
  float Aneg = -__expf(A_log[d*16 + n]);
  float h = 0.f;
  #pragma unroll
  for (int c=0;c<NC;c++){
    hin[(c*16+n)*4096 + bd] = h;
    float P = __expf(Aneg * sumDu[c*4096 + bd]);
    h = S[(c*16+n)*4096 + bd] + P*h;
  }
}

// phase3: within-chunk scan from hin; fused y = (sum_n h*C + xc*D)*silu(z) -> bf16
__global__ __launch_bounds__(256) void scan_p3(
    const float* __restrict__ delta, const float* __restrict__ xc,
    const float* __restrict__ xdbl, const bf16* __restrict__ xz,
    const float* __restrict__ A_log, const float* __restrict__ Dp,
    const float* __restrict__ hin, bf16* __restrict__ y)
{
  const int tid = threadIdx.x;
  const int d   = blockIdx.x*256 + tid;
  const int c   = blockIdx.y, b = blockIdx.z;
  const int bd  = b*2048 + d;
  DECL_AN(A_log, d);
  const float Dd = Dp[d];
  __shared__ float sB[CL][16], sC[CL][16];
  {
    int e = tid*2;
    int r = e>>4, n = e&15;
    long row = (long)b*LSEQ + c*CL + r;
    sB[r][n]   = xdbl[row*96 + 64 + n];
    sB[r][n+1] = xdbl[row*96 + 64 + n+1];
    sC[r][n]   = xdbl[row*96 + 80 + n];
    sC[r][n+1] = xdbl[row*96 + 80 + n+1];
  }
  __syncthreads();
  float h0,h1,h2,h3,h4,h5,h6,h7,h8,h9,h10,h11,h12,h13,h14,h15;
  {
    const float* hp = hin + c*16*4096 + bd;
    h0 =hp[0];       h1 =hp[4096];    h2 =hp[2*4096];  h3 =hp[3*4096];
    h4 =hp[4*4096];  h5 =hp[5*4096];  h6 =hp[6*4096];  h7 =hp[7*4096];
    h8 =hp[8*4096];  h9 =hp[9*4096];  h10=hp[10*4096]; h11=hp[11*4096];
    h12=hp[12*4096]; h13=hp[13*4096]; h14=hp[14*4096]; h15=hp[15*4096];
  }
  const long rbase = (long)b*LSEQ + c*CL;
  #pragma unroll
  for (int s0=0; s0<CL; s0+=8){
    float du8[8], xv8[8], zv8[8];
    #pragma unroll
    for (int i=0;i<8;i++){
      long row = rbase + s0 + i;
      du8[i] = delta[row*DI + d];
      xv8[i] = xc[row*DI + d];
      zv8[i] = __bfloat162float(xz[row*(2*DI) + DI + d]);
    }
    #pragma unroll
    for (int i=0;i<8;i++){
      float du = du8[i], xv = xv8[i], duxv = du*xv;
      const float4* bb = (const float4*)sB[s0+i];
      float4 B0=bb[0], B1=bb[1], B2=bb[2], B3=bb[3];
      H16(du, duxv, B0,B1,B2,B3);
      const float4* cc = (const float4*)sC[s0+i];
      float4 C0=cc[0], C1=cc[1], C2=cc[2], C3=cc[3];
      float r0 = h0*C0.x + h4*C1.x + h8 *C2.x + h12*C3.x;
      float r1 = h1*C0.y + h5*C1.y + h9 *C2.y + h13*C3.y;
      float r2 = h2*C0.z + h6*C1.z + h10*C2.z + h14*C3.z;
      float r3 = h3*C0.w + h7*C1.w + h11*C2.w + h15*C3.w;
      float r = (r0+r1) + (r2+r3) + xv*Dd;
      float z = zv8[i];
      y[(rbase+s0+i)*DI + d] = __float2bfloat16(r * (z*sigmoidf_(z)));
    }
  }
}

// ---------------- gated: g = silu(gv[:, :1024]) * gv[:, 1024:] -> bf16 -------------
__global__ __launch_bounds__(256) void gated_kernel(const float* __restrict__ gv,
                                                    bf16* __restrict__ g)
{
  long i = (long)blockIdx.x*blockDim.x + threadIdx.x;  // NROWS*DM
  int r = (int)(i >> 10);
  int c = (int)(i & (DM-1));
  float gt = gv[(long)r*(2*DM) + c];
  float vl = gv[(long)r*(2*DM) + DM + c];
  g[i] = __float2bfloat16(gt * sigmoidf_(gt) * vl);
}

// ------------------------------- launcher ------------------------------------------
extern "C" void kernel_launch(void* const* d_in, const int* in_sizes, int n_in,
                              void* d_out, int out_size, void* d_ws, size_t ws_size,
                              hipStream_t stream)
{
  const float* x        = (const float*)d_in[0];
  const float* n1_g     = (const float*)d_in[1];
  const float* n1_b     = (const float*)d_in[2];
  const float* n2_g     = (const float*)d_in[3];
  const float* n2_b     = (const float*)d_in[4];
  const float* in_proj_w= (const float*)d_in[5];
  const float* conv_w   = (const float*)d_in[6];
  const float* conv_b   = (const float*)d_in[7];
  const float* x_proj_w = (const float*)d_in[8];
  const float* dt_w     = (const float*)d_in[9];
  const float* dt_b     = (const float*)d_in[10];
  const float* A_log    = (const float*)d_in[11];
  const float* Dp       = (const float*)d_in[12];
  const float* out_w    = (const float*)d_in[13];
  const float* ffg_w    = (const float*)d_in[14];
  const float* ffg_b    = (const float*)d_in[15];
  const float* ffp_w    = (const float*)d_in[16];
  const float* ffp_b    = (const float*)d_in[17];

  char* ws = (char*)d_ws;
  // bf16 buffers
  bf16* w_inproj = (bf16*)(ws + 0);          // 4096x1024
  bf16* w_xproj  = (bf16*)(ws + 8388608);    // 128x2048 (zero-pad from 96 rows)
  bf16* w_dt     = (bf16*)(ws + 8912896);    // 2048x64
  bf16* w_out    = (bf16*)(ws + 9175040);    // 1024x2048
  bf16* w_ffg    = (bf16*)(ws + 13369344);   // 2048x1024
  bf16* w_ffp    = (bf16*)(ws + 17563648);   // 1024x1024
  bf16* x1_b     = (bf16*)(ws + 19660800);   // 2048x1024 (reused: normed)
  bf16* xz_b     = (bf16*)(ws + 23855104);   // 2048x4096 (dead after scan_p3 ->
  float* part_fp = (float*)(ws + 23855104);  //   reused: ffp split-K partials 2x8.4MB)
  bf16* xc_b     = (bf16*)(ws + 40632320);   // 2048x2048 (dead after x_proj)
  float* S_buf   = (float*)(ws + 40632320);  //   reused: scan S [32c][16n][4096bd] = 8 MB
  float* sumDu   = (float*)(ws + 8388608);   //   reused (w_xproj dead): [32c][4096bd] = 512 KB
  bf16* dt16     = (bf16*)(ws + 49020928);   // 2048x64
  bf16* y_b      = (bf16*)(ws + 49283072);   // 2048x2048 (reused: g 2048x1024)
  // f32 buffers
  float* xc_f    = (float*)(ws + 57671680);  // 2048x2048
  float* xdbl_f  = (float*)(ws + 74448896);  // 2048x96
  float* delta_f = (float*)(ws + 75235328);  // 2048x2048 (pre-used: x_proj partials;
  float* part_xp = (float*)(ws + 75235328);  //   reused: out_proj partials; then gv)
  float* part_op = (float*)(ws + 75235328);  //   out_proj split-K partials 2x8.4MB
  float* x2_f    = (float*)(ws + 92012544);  // 2048x1024 (first 8MB pre-used as hin)
  float* hin     = (float*)(ws + 92012544);  // [32c][16n][4096bd] = 8 MB (dead before x2 write)
  float* outp    = (float*)d_out;            // 2048x1024

  #define GRID1(n) dim3((int)(((n)+255)/256))
  // weight converts
  cvt_kernel<<<GRID1(4096L*1024), 256, 0, stream>>>(in_proj_w, w_inproj, 4096L*1024, 1024, 1024, 4096);
  cvt_kernel<<<GRID1(128L*2048), 256, 0, stream>>>(x_proj_w,  w_xproj,  128L*2048, 2048, 2048, 96);
  cvt_kernel<<<GRID1(2048L*64),  256, 0, stream>>>(dt_w,      w_dt,     2048L*64,   64,   64, 2048);
  cvt_kernel<<<GRID1(1024L*2048),256, 0, stream>>>(out_w,     w_out,    1024L*2048, 2048, 2048, 1024);
  cvt_kernel<<<GRID1(2048L*1024),256, 0, stream>>>(ffg_w,     w_ffg,    2048L*1024, 1024, 1024, 2048);
  cvt_kernel<<<GRID1(1024L*1024),256, 0, stream>>>(ffp_w,     w_ffp,    1024L*1024, 1024, 1024, 1024);

  // 1) x1 = LN(x)
  ln_kernel<<<NROWS, 256, 0, stream>>>(x, n1_g, n1_b, x1_b);
  // 2) xz = x1 @ in_proj_w^T   [2048 x 4096]  (512 wg)
  gemm_k<0><<<dim3(16,32), 256, 0, stream>>>((const short*)x1_b, 1024, (const short*)w_inproj, 1024,
      1024, 4096, 4096, 0, nullptr, nullptr, nullptr, xz_b);
  // 3) xc = silu(causal_conv(x_in)+cb)
  conv_kernel<<<GRID1((long)NROWS*DI), 256, 0, stream>>>(xz_b, conv_w, conv_b, xc_f, xc_b);
  // 4) x_dbl partials = xc @ x_proj_w^T  [2048 x 96], split-K 8x256
  gemm_k<0><<<dim3(16,1,8), 256, 0, stream>>>((const short*)xc_b, 2048, (const short*)w_xproj, 2048,
      256, 96, 96, NROWS*96, nullptr, nullptr, part_xp, nullptr);
  // 5) reduce partials -> xdbl_f (+ dt16 bf16 slice)
  xproj_reduce<<<GRID1((long)NROWS*96), 256, 0, stream>>>(part_xp, xdbl_f, dt16);
  // 6) delta = softplus(dt @ dt_w^T + dt_b)  [2048 x 2048]
  gemm_k<1><<<dim3(16,16), 256, 0, stream>>>((const short*)dt16, 64, (const short*)w_dt, 64,
      64, 2048, 2048, 0, dt_b, nullptr, delta_f, nullptr);
  // 7) chunked scan (states-in-registers) -> y (bf16), fused +xc*D and *silu(z)
  scan_p1<<<dim3(8,NC,2), 256, 0, stream>>>(delta_f, xc_f, xdbl_f, A_log, S_buf, sumDu);
  scan_p2<<<dim3(256), 256, 0, stream>>>(S_buf, sumDu, A_log, hin);
  scan_p3<<<dim3(8,NC,2), 256, 0, stream>>>(delta_f, xc_f, xdbl_f, xz_b, A_log, Dp, hin, y_b);
  // 8) x2 = x + y @ out_w^T  [2048 x 1024], split-K 2x1024 (512 wg total)
  gemm_k<0><<<dim3(16,8,2), 256, 0, stream>>>((const short*)y_b, 2048, (const short*)w_out, 2048,
      1024, 1024, 1024, NROWS*DM, nullptr, nullptr, part_op, nullptr);
  red2_kernel<<<dim3(2048), 256, 0, stream>>>(part_op, part_op + (long)NROWS*DM, nullptr, x, x2_f);
  // 9) normed = LN(x2)  (reuse x1_b)
  ln_kernel<<<NROWS, 256, 0, stream>>>(x2_f, n2_g, n2_b, x1_b);
  // 10) gv = normed @ ffg_w^T + ffg_b  [2048 x 2048]  (256 wg; reuse delta_f)
  gemm_k<0><<<dim3(16,16), 256, 0, stream>>>((const short*)x1_b, 1024, (const short*)w_ffg, 1024,
      1024, 2048, 2048, 0, ffg_b, nullptr, delta_f, nullptr);
  // 11) g = silu(gate)*val -> bf16 (reuse y_b)
  gated_kernel<<<GRID1((long)NROWS*DM), 256, 0, stream>>>(delta_f, y_b);
  // 12) out = x2 + g @ ffp_w^T + ffp_b, split-K 2x512 (512 wg total; partials in xz_b)
  gemm_k<0><<<dim3(16,8,2), 256, 0, stream>>>((const short*)y_b, 1024, (const short*)w_ffp, 1024,
      512, 1024, 1024, NROWS*DM, nullptr, nullptr, part_fp, nullptr);
  red2_kernel<<<dim3(2048), 256, 0, stream>>>(part_fp, part_fp + (long)NROWS*DM, ffp_b, x2_f, outp);
  #undef GRID1
}

// Round 13
// 348.131 us; speedup vs baseline: 2.4606x; 1.0772x over previous
//
#include <hip/hip_runtime.h>
#include <hip/hip_bf16.h>

#define DM 1024
#define DI 2048
#define LSEQ 1024
#define BSZ 2
#define NROWS (BSZ*LSEQ)   // 2048
#define NC 32              // scan chunks
#define CL 32              // chunk length (NC*CL = LSEQ)

typedef __attribute__((ext_vector_type(4))) float f32x4;
typedef __attribute__((ext_vector_type(8))) short bf16x8;
typedef __attribute__((ext_vector_type(4))) short s16x4;
typedef __hip_bfloat16 bf16;

__device__ __forceinline__ float sigmoidf_(float x){ return 1.f/(1.f+__expf(-x)); }
__device__ __forceinline__ short bfbits(float x){ bf16 h=__float2bfloat16(x); return *reinterpret_cast<short*>(&h); }

// ---------------- ALL weight converts in ONE kernel (compile-time segments) ---------
// seg0 in_proj 4096x1024 | seg1 x_proj pad 96->128 rows x2048 | seg2 dt 2048x64
// seg3 out 1024x2048 | seg4 ffg 2048x1024 | seg5 ffp 1024x1024. 4 elems/thread.
#define U0 1048576L
#define U1 (U0+65536L)
#define U2 (U1+32768L)
#define U3 (U2+524288L)
#define U4 (U3+524288L)
#define U5 (U4+262144L)   // 2457600 units total
__global__ __launch_bounds__(256) void cvt_all(
    const float* __restrict__ s0, const float* __restrict__ s1, const float* __restrict__ s2,
    const float* __restrict__ s3, const float* __restrict__ s4, const float* __restrict__ s5,
    bf16* __restrict__ d0, bf16* __restrict__ d1, bf16* __restrict__ d2,
    bf16* __restrict__ d3, bf16* __restrict__ d4, bf16* __restrict__ d5)
{
  long u = (long)blockIdx.x*256 + threadIdx.x;
  if (u >= U5) return;
  const float* src; bf16* dst; long e;
  if (u < U0)      { src=s0; dst=d0; e=u*4; }
  else if (u < U1) { // x_proj: zero-pad rows >= 96
    long v=u-U0; e=v*4; long row=e>>11;
    s16x4 o;
    if (row < 96){
      float4 x = *(const float4*)(s1 + e);
      o[0]=bfbits(x.x); o[1]=bfbits(x.y); o[2]=bfbits(x.z); o[3]=bfbits(x.w);
    } else { o[0]=o[1]=o[2]=o[3]=0; }
    *(s16x4*)(d1+e) = o; return;
  }
  else if (u < U2) { src=s2; dst=d2; e=(u-U1)*4; }
  else if (u < U3) { src=s3; dst=d3; e=(u-U2)*4; }
  else if (u < U4) { src=s4; dst=d4; e=(u-U3)*4; }
  else             { src=s5; dst=d5; e=(u-U4)*4; }
  float4 x = *(const float4*)(src + e);
  s16x4 o; o[0]=bfbits(x.x); o[1]=bfbits(x.y); o[2]=bfbits(x.z); o[3]=bfbits(x.w);
  *(s16x4*)(dst+e) = o;
}

// ---------------- LayerNorm (row=1024) f32 -> bf16 ----------------
__global__ __launch_bounds__(256) void ln_kernel(const float* __restrict__ x,
    const float* __restrict__ g, const float* __restrict__ b, bf16* __restrict__ out)
{
  int row = blockIdx.x;
  float4 v = ((const float4*)(x + (long)row*DM))[threadIdx.x];
  float s  = v.x+v.y+v.z+v.w;
  float s2 = v.x*v.x+v.y*v.y+v.z*v.z+v.w*v.w;
  #pragma unroll
  for (int m=32;m;m>>=1){ s += __shfl_xor(s,m); s2 += __shfl_xor(s2,m); }
  __shared__ float ws0[4], ws1[4];
  int wv = threadIdx.x>>6;
  if ((threadIdx.x&63)==0){ ws0[wv]=s; ws1[wv]=s2; }
  __syncthreads();
  s  = ws0[0]+ws0[1]+ws0[2]+ws0[3];
  s2 = ws1[0]+ws1[1]+ws1[2]+ws1[3];
  float mu  = s*(1.f/DM);
  float var = s2*(1.f/DM) - mu*mu;
  float rs  = rsqrtf(var + 1e-5f);
  int c = threadIdx.x*4;
  float4 gg = ((const float4*)g)[threadIdx.x];
  float4 bb = ((const float4*)b)[threadIdx.x];
  bf16* o = out + (long)row*DM + c;
  o[0] = __float2bfloat16((v.x-mu)*rs*gg.x + bb.x);
  o[1] = __float2bfloat16((v.y-mu)*rs*gg.y + bb.y);
  o[2] = __float2bfloat16((v.z-mu)*rs*gg.z + bb.z);
  o[3] = __float2bfloat16((v.w-mu)*rs*gg.w + bb.w);
}

// ---------------- bf16 MFMA GEMM: C[M,N] = A[M,K] @ B[N,K]^T (+bias)(+act)(+res) ----
// 128x128 tile, 256 threads (4 waves), each wave 64x64 via 4x4 frags of 16x16x32.
// Depth-3 pipeline, 4 LDS buffers, counted vmcnt(8) (T3/T4 minimum): never drain
// vmcnt to 0 in the main loop. ONE barrier per K-step (buffers disjoint by depth<nbuf).
// ACT: 0=none, 1=softplus. blockIdx.z = K-split (A,B advance z*K; outf by z*pstride).
template<int ACT>
__global__ __launch_bounds__(256)
void gemm_k(const short* __restrict__ A, int lda, const short* __restrict__ B, int ldb,
            int K, int Nreal, int ldo, int pstride,
            const float* __restrict__ bias, const float* __restrict__ res,
            float* __restrict__ outf, bf16* __restrict__ outb)
{
  A += (size_t)blockIdx.z * K;
  B += (size_t)blockIdx.z * K;
  if (outf) outf += (size_t)blockIdx.z * pstride;

  __shared__ short As[4][128*32];
  __shared__ short Bs[4][128*32];
  const int tid  = threadIdx.x;
  const int wave = tid>>6, lane = tid&63;
  const int m0 = blockIdx.x*128, n0 = blockIdx.y*128;
  const int wm = (wave>>1)*64, wn = (wave&1)*64;
  const int lr = lane&15, lk = lane>>4;

  f32x4 acc[4][4];
  #pragma unroll
  for (int i=0;i<4;i++)
    #pragma unroll
    for (int j=0;j<4;j++) acc[i][j] = f32x4{0.f,0.f,0.f,0.f};

  const int r0 = tid>>2;        // 0..63
  const int kb = (tid&3)*8;     // 0,8,16,24 (bf16 elems)
  const short* Arow = A + (size_t)(m0+r0)*lda + kb;
  const short* Brow = B + (size_t)(n0+r0)*ldb + kb;

#define STAGE_T(buf, kt) do { \
    __builtin_amdgcn_global_load_lds((const __attribute__((address_space(1))) void*)(Arow + (kt)), \
        (__attribute__((address_space(3))) void*)(&As[buf][r0*32+kb]), 16, 0, 0); \
    __builtin_amdgcn_global_load_lds((const __attribute__((address_space(1))) void*)(Arow + (size_t)64*lda + (kt)), \
        (__attribute__((address_space(3))) void*)(&As[buf][(r0+64)*32+kb]), 16, 0, 0); \
    __builtin_amdgcn_global_load_lds((const __attribute__((address_space(1))) void*)(Brow + (kt)), \
        (__attribute__((address_space(3))) void*)(&Bs[buf][r0*32+kb]), 16, 0, 0); \
    __builtin_amdgcn_global_load_lds((const __attribute__((address_space(1))) void*)(Brow + (size_t)64*ldb + (kt)), \
        (__attribute__((address_space(3))) void*)(&Bs[buf][(r0+64)*32+kb]), 16, 0, 0); \
  } while(0)

  const int nt = K >> 5;
  {
    const int pre = nt < 3 ? nt : 3;
    for (int s=0; s<pre; ++s) STAGE_T(s, s*32);
  }
  for (int t=0; t<nt; ++t) {
    // counted wait: retire ONLY the oldest stage (4 loads); keep 2 stages in flight
    if (t <= nt-3)      asm volatile("s_waitcnt vmcnt(8)");
    else if (t == nt-2) asm volatile("s_waitcnt vmcnt(4)");
    else                asm volatile("s_waitcnt vmcnt(0)");
    __syncthreads();
    const int cur = t & 3;
    bf16x8 af[4], bfr[4];
    #pragma unroll
    for (int i=0;i<4;i++) af[i]  = *(const bf16x8*)(&As[cur][(wm+i*16+lr)*32 + lk*8]);
    #pragma unroll
    for (int j=0;j<4;j++) bfr[j] = *(const bf16x8*)(&Bs[cur][(wn+j*16+lr)*32 + lk*8]);
    #pragma unroll
    for (int i=0;i<4;i++)
      #pragma unroll
      for (int j=0;j<4;j++)
        acc[i][j] = __builtin_amdgcn_mfma_f32_16x16x32_bf16(af[i], bfr[j], acc[i][j], 0,0,0);
    if (t+3 < nt) STAGE_T((t+3)&3, (t+3)*32);
  }
#undef STAGE_T

  // epilogue: C/D map col=lane&15, row=(lane>>4)*4+reg   [m89-verified]
  #pragma unroll
  for (int i=0;i<4;i++){
    #pragma unroll
    for (int j=0;j<4;j++){
      int col = n0 + wn + j*16 + lr;
      if (col >= Nreal) continue;
      #pragma unroll
      for (int r=0;r<4;r++){
        int row = m0 + wm + i*16 + lk*4 + r;
        float v = acc[i][j][r];
        if (bias) v += bias[col];
        if (ACT==1){
          float ev = __expf(v);
          v = (v > 20.f) ? v : __logf(1.f + ev);
        }
        if (res)  v += res[(size_t)row*ldo + col];
        if (outf) outf[(size_t)row*ldo + col] = v;
        if (outb) outb[(size_t)row*ldo + col] = __float2bfloat16(v);
      }
    }
  }
}

// ---------------- split-K=2 reduce: out = p0+p1 (+bias) (+res) -> f32 ---------------
__global__ __launch_bounds__(256) void red2_kernel(
    const float* __restrict__ p0, const float* __restrict__ p1,
    const float* __restrict__ bias, const float* __restrict__ res,
    float* __restrict__ outf)
{
  long i = ((long)blockIdx.x*256 + threadIdx.x)*4;   // over 2048x1024 f32
  float4 a = *(const float4*)(p0+i);
  float4 b = *(const float4*)(p1+i);
  float4 o = {a.x+b.x, a.y+b.y, a.z+b.z, a.w+b.w};
  if (bias){
    const float4 bb = *(const float4*)(bias + (int)(i & (DM-1)));
    o.x+=bb.x; o.y+=bb.y; o.z+=bb.z; o.w+=bb.w;
  }
  if (res){
    float4 r = *(const float4*)(res+i);
    o.x+=r.x; o.y+=r.y; o.z+=r.z; o.w+=r.w;
  }
  *(float4*)(outf+i) = o;
}

// ---------------- split-K reduce for x_proj; fuses dt bf16 slice --------------------
__global__ __launch_bounds__(256) void xproj_reduce(const float* __restrict__ part,
    float* __restrict__ xdbl, bf16* __restrict__ dt16)
{
  int i = blockIdx.x*256 + threadIdx.x;
  if (i >= NROWS*96) return;
  float s = 0.f;
  #pragma unroll
  for (int k=0;k<8;k++) s += part[(long)k*(NROWS*96) + i];
  xdbl[i] = s;
  int r = i/96, c = i - r*96;
  if (c < 64) dt16[r*64 + c] = __float2bfloat16(s);
}

// ---------------- depthwise causal conv(4) + silu; writes f32 + bf16 ----------------
__global__ __launch_bounds__(256) void conv_kernel(const bf16* __restrict__ xz,
    const float* __restrict__ w, const float* __restrict__ cb,
    float* __restrict__ xcf, bf16* __restrict__ xcb)
{
  long i = (long)blockIdx.x*blockDim.x + threadIdx.x;  // NROWS*DI
  int d  = (int)(i & (DI-1));
  int bl = (int)(i >> 11);
  int l  = bl & (LSEQ-1);
  int b  = bl >> 10;
  float acc = cb[d];
  #pragma unroll
  for (int k=0;k<4;k++){
    int ls = l-3+k;
    if (ls >= 0)
      acc += __bfloat162float(xz[(long)(b*LSEQ+ls)*(2*DI) + d]) * w[d*4+k];
  }
  float s = acc * sigmoidf_(acc);
  xcf[i] = s;
  xcb[i] = __float2bfloat16(s);
}

// ======================= chunked SSM scan, states-in-registers ======================
#define H16(du, duxv, B0,B1,B2,B3) \
  h0  = __expf((du)*An0 )*h0  + (duxv)*(B0).x; \
  h1  = __expf((du)*An1 )*h1  + (duxv)*(B0).y; \
  h2  = __expf((du)*An2 )*h2  + (duxv)*(B0).z; \
  h3  = __expf((du)*An3 )*h3  + (duxv)*(B0).w; \
  h4  = __expf((du)*An4 )*h4  + (duxv)*(B1).x; \
  h5  = __expf((du)*An5 )*h5  + (duxv)*(B1).y; \
  h6  = __expf((du)*An6 )*h6  + (duxv)*(B1).z; \
  h7  = __expf((du)*An7 )*h7  + (duxv)*(B1).w; \
  h8  = __expf((du)*An8 )*h8  + (duxv)*(B2).x; \
  h9  = __expf((du)*An9 )*h9  + (duxv)*(B2).y; \
  h10 = __expf((du)*An10)*h10 + (duxv)*(B2).z; \
  h11 = __expf((du)*An11)*h11 + (duxv)*(B2).w; \
  h12 = __expf((du)*An12)*h12 + (duxv)*(B3).x; \
  h13 = __expf((du)*An13)*h13 + (duxv)*(B3).y; \
  h14 = __expf((du)*An14)*h14 + (duxv)*(B3).z; \
  h15 = __expf((du)*An15)*h15 + (duxv)*(B3).w;

#define DECL_AN(Alog_ptr, d) \
  float4 al0 = ((const float4*)((Alog_ptr) + (d)*16))[0]; \
  float4 al1 = ((const float4*)((Alog_ptr) + (d)*16))[1]; \
  float4 al2 = ((const float4*)((Alog_ptr) + (d)*16))[2]; \
  float4 al3 = ((const float4*)((Alog_ptr) + (d)*16))[3]; \
  float An0=-__expf(al0.x), An1=-__expf(al0.y), An2 =-__expf(al0.z), An3 =-__expf(al0.w); \
  float An4=-__expf(al1.x), An5=-__expf(al1.y), An6 =-__expf(al1.z), An7 =-__expf(al1.w); \
  float An8=-__expf(al2.x), An9=-__expf(al2.y), An10=-__expf(al2.z), An11=-__expf(al2.w); \
  float An12=-__expf(al3.x),An13=-__expf(al3.y),An14=-__expf(al3.z), An15=-__expf(al3.w);

// phase1: per-chunk S (scan from 0) + sumDu
__global__ __launch_bounds__(256) void scan_p1(
    const float* __restrict__ delta, const float* __restrict__ xc,
    const float* __restrict__ xdbl, const float* __restrict__ A_log,
    float* __restrict__ S, float* __restrict__ sumDu)
{
  const int tid = threadIdx.x;
  const int d   = blockIdx.x*256 + tid;
  const int c   = blockIdx.y, b = blockIdx.z;
  const int bd  = b*2048 + d;
  DECL_AN(A_log, d);
  __shared__ float sB[CL][16];
  {
    int e = tid*2;
    int r = e>>4, n = e&15;
    long row = (long)b*LSEQ + c*CL + r;
    sB[r][n]   = xdbl[row*96 + 64 + n];
    sB[r][n+1] = xdbl[row*96 + 64 + n+1];
  }
  __syncthreads();
  float h0=0,h1=0,h2=0,h3=0,h4=0,h5=0,h6=0,h7=0,
        h8=0,h9=0,h10=0,h11=0,h12=0,h13=0,h14=0,h15=0;
  float sdu = 0.f;
  const long rbase = (long)b*LSEQ + c*CL;
  #pragma unroll
  for (int s0=0; s0<CL; s0+=8){
    float du8[8], xv8[8];
    #pragma unroll
    for (int i=0;i<8;i++){
      long row = rbase + s0 + i;
      du8[i] = delta[row*DI + d];
      xv8[i] = xc[row*DI + d];
    }
    #pragma unroll
    for (int i=0;i<8;i++){
      float du = du8[i], duxv = du*xv8[i];
      sdu += du;
      const float4* bb = (const float4*)sB[s0+i];
      float4 B0=bb[0], B1=bb[1], B2=bb[2], B3=bb[3];
      H16(du, duxv, B0,B1,B2,B3);
    }
  }
  sumDu[c*4096 + bd] = sdu;
  float hs[16] = {h0,h1,h2,h3,h4,h5,h6,h7,h8,h9,h10,h11,h12,h13,h14,h15};
  #pragma unroll
  for (int n=0;n<16;n++) S[(c*16+n)*4096 + bd] = hs[n];
}

// phase2: compose carries serially over chunks -> per-chunk initial state
__global__ __launch_bounds__(256) void scan_p2(const float* __restrict__ S,
    const float* __restrict__ sumDu, const float* __restrict__ A_log,
    float* __restrict__ hin)
{
  int t = blockIdx.x*256 + threadIdx.x;    // 65536 = 16n * 4096bd
  int n = t >> 12, bd = t & 4095;
  int d = bd & 2047;
  float Aneg = -__expf(A_log[d*16 + n]);
  float h = 0.f;
  #pragma unroll
  for (int c=0;c<NC;c++){
    hin[(c*16+n)*4096 + bd] = h;
    float P = __expf(Aneg * sumDu[c*4096 + bd]);
    h = S[(c*16+n)*4096 + bd] + P*h;
  }
}

// phase3: within-chunk scan from hin; fused y = (sum_n h*C + xc*D)*silu(z) -> bf16
__global__ __launch_bounds__(256) void scan_p3(
    const float* __restrict__ delta, const float* __restrict__ xc,
    const float* __restrict__ xdbl, const bf16* __restrict__ xz,
    const float* __restrict__ A_log, const float* __restrict__ Dp,
    const float* __restrict__ hin, bf16* __restrict__ y)
{
  const int tid = threadIdx.x;
  const int d   = blockIdx.x*256 + tid;
  const int c   = blockIdx.y, b = blockIdx.z;
  const int bd  = b*2048 + d;
  DECL_AN(A_log, d);
  const float Dd = Dp[d];
  __shared__ float sB[CL][16], sC[CL][16];
  {
    int e = tid*2;
    int r = e>>4, n = e&15;
    long row = (long)b*LSEQ + c*CL + r;
    sB[r][n]   = xdbl[row*96 + 64 + n];
    sB[r][n+1] = xdbl[row*96 + 64 + n+1];
    sC[r][n]   = xdbl[row*96 + 80 + n];
    sC[r][n+1] = xdbl[row*96 + 80 + n+1];
  }
  __syncthreads();
  float h0,h1,h2,h3,h4,h5,h6,h7,h8,h9,h10,h11,h12,h13,h14,h15;
  {
    const float* hp = hin + c*16*4096 + bd;
    h0 =hp[0];       h1 =hp[4096];    h2 =hp[2*4096];  h3 =hp[3*4096];
    h4 =hp[4*4096];  h5 =hp[5*4096];  h6 =hp[6*4096];  h7 =hp[7*4096];
    h8 =hp[8*4096];  h9 =hp[9*4096];  h10=hp[10*4096]; h11=hp[11*4096];
    h12=hp[12*4096]; h13=hp[13*4096]; h14=hp[14*4096]; h15=hp[15*4096];
  }
  const long rbase = (long)b*LSEQ + c*CL;
  #pragma unroll
  for (int s0=0; s0<CL; s0+=8){
    float du8[8], xv8[8], zv8[8];
    #pragma unroll
    for (int i=0;i<8;i++){
      long row = rbase + s0 + i;
      du8[i] = delta[row*DI + d];
      xv8[i] = xc[row*DI + d];
      zv8[i] = __bfloat162float(xz[row*(2*DI) + DI + d]);
    }
    #pragma unroll
    for (int i=0;i<8;i++){
      float du = du8[i], xv = xv8[i], duxv = du*xv;
      const float4* bb = (const float4*)sB[s0+i];
      float4 B0=bb[0], B1=bb[1], B2=bb[2], B3=bb[3];
      H16(du, duxv, B0,B1,B2,B3);
      const float4* cc = (const float4*)sC[s0+i];
      float4 C0=cc[0], C1=cc[1], C2=cc[2], C3=cc[3];
      float r0 = h0*C0.x + h4*C1.x + h8 *C2.x + h12*C3.x;
      float r1 = h1*C0.y + h5*C1.y + h9 *C2.y + h13*C3.y;
      float r2 = h2*C0.z + h6*C1.z + h10*C2.z + h14*C3.z;
      float r3 = h3*C0.w + h7*C1.w + h11*C2.w + h15*C3.w;
      float r = (r0+r1) + (r2+r3) + xv*Dd;
      float z = zv8[i];
      y[(rbase+s0+i)*DI + d] = __float2bfloat16(r * (z*sigmoidf_(z)));
    }
  }
}

// ---------------- gated: g = silu(gv[:, :1024]) * gv[:, 1024:] -> bf16 -------------
__global__ __launch_bounds__(256) void gated_kernel(const float* __restrict__ gv,
                                                    bf16* __restrict__ g)
{
  long i = (long)blockIdx.x*blockDim.x + threadIdx.x;  // NROWS*DM
  int r = (int)(i >> 10);
  int c = (int)(i & (DM-1));
  float gt = gv[(long)r*(2*DM) + c];
  float vl = gv[(long)r*(2*DM) + DM + c];
  g[i] = __float2bfloat16(gt * sigmoidf_(gt) * vl);
}

// ------------------------------- launcher ------------------------------------------
extern "C" void kernel_launch(void* const* d_in, const int* in_sizes, int n_in,
                              void* d_out, int out_size, void* d_ws, size_t ws_size,
                              hipStream_t stream)
{
  const float* x        = (const float*)d_in[0];
  const float* n1_g     = (const float*)d_in[1];
  const float* n1_b     = (const float*)d_in[2];
  const float* n2_g     = (const float*)d_in[3];
  const float* n2_b     = (const float*)d_in[4];
  const float* in_proj_w= (const float*)d_in[5];
  const float* conv_w   = (const float*)d_in[6];
  const float* conv_b   = (const float*)d_in[7];
  const float* x_proj_w = (const float*)d_in[8];
  const float* dt_w     = (const float*)d_in[9];
  const float* dt_b     = (const float*)d_in[10];
  const float* A_log    = (const float*)d_in[11];
  const float* Dp       = (const float*)d_in[12];
  const float* out_w    = (const float*)d_in[13];
  const float* ffg_w    = (const float*)d_in[14];
  const float* ffg_b    = (const float*)d_in[15];
  const float* ffp_w    = (const float*)d_in[16];
  const float* ffp_b    = (const float*)d_in[17];

  char* ws = (char*)d_ws;
  // bf16 buffers
  bf16* w_inproj = (bf16*)(ws + 0);          // 4096x1024
  bf16* w_xproj  = (bf16*)(ws + 8388608);    // 128x2048 (zero-pad from 96 rows)
  bf16* w_dt     = (bf16*)(ws + 8912896);    // 2048x64
  bf16* w_out    = (bf16*)(ws + 9175040);    // 1024x2048
  bf16* w_ffg    = (bf16*)(ws + 13369344);   // 2048x1024
  bf16* w_ffp    = (bf16*)(ws + 17563648);   // 1024x1024
  bf16* x1_b     = (bf16*)(ws + 19660800);   // 2048x1024 (reused: normed)
  bf16* xz_b     = (bf16*)(ws + 23855104);   // 2048x4096 (dead after scan_p3 ->
  float* part_fp = (float*)(ws + 23855104);  //   reused: ffp split-K partials 2x8.4MB)
  bf16* xc_b     = (bf16*)(ws + 40632320);   // 2048x2048 (dead after x_proj)
  float* S_buf   = (float*)(ws + 40632320);  //   reused: scan S [32c][16n][4096bd] = 8 MB
  float* sumDu   = (float*)(ws + 8388608);   //   reused (w_xproj dead): [32c][4096bd] = 512 KB
  bf16* dt16     = (bf16*)(ws + 49020928);   // 2048x64
  bf16* y_b      = (bf16*)(ws + 49283072);   // 2048x2048 (reused: g 2048x1024)
  // f32 buffers
  float* xc_f    = (float*)(ws + 57671680);  // 2048x2048
  float* xdbl_f  = (float*)(ws + 74448896);  // 2048x96
  float* delta_f = (float*)(ws + 75235328);  // 2048x2048 (pre-used: x_proj partials;
  float* part_xp = (float*)(ws + 75235328);  //   reused: out_proj partials; then gv)
  float* part_op = (float*)(ws + 75235328);  //   out_proj split-K partials 2x8.4MB
  float* x2_f    = (float*)(ws + 92012544);  // 2048x1024 (first 8MB pre-used as hin)
  float* hin     = (float*)(ws + 92012544);  // [32c][16n][4096bd] = 8 MB (dead before x2 write)
  float* outp    = (float*)d_out;            // 2048x1024

  #define GRID1(n) dim3((int)(((n)+255)/256))
  // 0) ALL weight converts in one dispatch (2457600 4-elem units)
  cvt_all<<<dim3(9600), 256, 0, stream>>>(in_proj_w, x_proj_w, dt_w, out_w, ffg_w, ffp_w,
                                          w_inproj, w_xproj, w_dt, w_out, w_ffg, w_ffp);

  // 1) x1 = LN(x)
  ln_kernel<<<NROWS, 256, 0, stream>>>(x, n1_g, n1_b, x1_b);
  // 2) xz = x1 @ in_proj_w^T   [2048 x 4096]  (512 wg)
  gemm_k<0><<<dim3(16,32), 256, 0, stream>>>((const short*)x1_b, 1024, (const short*)w_inproj, 1024,
      1024, 4096, 4096, 0, nullptr, nullptr, nullptr, xz_b);
  // 3) xc = silu(causal_conv(x_in)+cb)
  conv_kernel<<<GRID1((long)NROWS*DI), 256, 0, stream>>>(xz_b, conv_w, conv_b, xc_f, xc_b);
  // 4) x_dbl partials = xc @ x_proj_w^T  [2048 x 96], split-K 8x256
  gemm_k<0><<<dim3(16,1,8), 256, 0, stream>>>((const short*)xc_b, 2048, (const short*)w_xproj, 2048,
      256, 96, 96, NROWS*96, nullptr, nullptr, part_xp, nullptr);
  // 5) reduce partials -> xdbl_f (+ dt16 bf16 slice)
  xproj_reduce<<<GRID1((long)NROWS*96), 256, 0, stream>>>(part_xp, xdbl_f, dt16);
  // 6) delta = softplus(dt @ dt_w^T + dt_b)  [2048 x 2048]
  gemm_k<1><<<dim3(16,16), 256, 0, stream>>>((const short*)dt16, 64, (const short*)w_dt, 64,
      64, 2048, 2048, 0, dt_b, nullptr, delta_f, nullptr);
  // 7) chunked scan (states-in-registers) -> y (bf16), fused +xc*D and *silu(z)
  scan_p1<<<dim3(8,NC,2), 256, 0, stream>>>(delta_f, xc_f, xdbl_f, A_log, S_buf, sumDu);
  scan_p2<<<dim3(256), 256, 0, stream>>>(S_buf, sumDu, A_log, hin);
  scan_p3<<<dim3(8,NC,2), 256, 0, stream>>>(delta_f, xc_f, xdbl_f, xz_b, A_log, Dp, hin, y_b);
  // 8) x2 = x + y @ out_w^T  [2048 x 1024], split-K 2x1024 (512 wg total)
  gemm_k<0><<<dim3(16,8,2), 256, 0, stream>>>((const short*)y_b, 2048, (const short*)w_out, 2048,
      1024, 1024, 1024, NROWS*DM, nullptr, nullptr, part_op, nullptr);
  red2_kernel<<<dim3(2048), 256, 0, stream>>>(part_op, part_op + (long)NROWS*DM, nullptr, x, x2_f);
  // 9) normed = LN(x2)  (reuse x1_b)
  ln_kernel<<<NROWS, 256, 0, stream>>>(x2_f, n2_g, n2_b, x1_b);
  // 10) gv = normed @ ffg_w^T + ffg_b  [2048 x 2048]  (256 wg; reuse delta_f)
  gemm_k<0><<<dim3(16,16), 256, 0, stream>>>((const short*)x1_b, 1024, (const short*)w_ffg, 1024,
      1024, 2048, 2048, 0, ffg_b, nullptr, delta_f, nullptr);
  // 11) g = silu(gate)*val -> bf16 (reuse y_b)
  gated_kernel<<<GRID1((long)NROWS*DM), 256, 0, stream>>>(delta_f, y_b);
  // 12) out = x2 + g @ ffp_w^T + ffp_b, split-K 2x512 (512 wg total; partials in xz_b)
  gemm_k<0><<<dim3(16,8,2), 256, 0, stream>>>((const short*)y_b, 1024, (const short*)w_ffp, 1024,
      512, 1024, 1024, NROWS*DM, nullptr, nullptr, part_fp, nullptr);
  red2_kernel<<<dim3(2048), 256, 0, stream>>>(part_fp, part_fp + (long)NROWS*DM, ffp_b, x2_f, outp);
  #undef GRID1
}